// Round 19
// baseline (267.686 us; speedup 1.0000x reference)
//
#include <hip/hip_runtime.h>
#include <math.h>

constexpr int SEQ  = 4096;
constexpr int DIM  = 512;
constexpr int NH   = 8;
constexpr int HDIM = 64;
constexpr int FFD  = 2048;
constexpr int KSPLIT = 3;

typedef unsigned short u16;
typedef __attribute__((ext_vector_type(8))) short bf16x8;
typedef __attribute__((ext_vector_type(4))) float f32x4;
typedef __attribute__((ext_vector_type(8))) unsigned short u16x8;

// score scale: (1/8) * log2(e), folded into wq. Softmax computed in exp2 domain.
// NO static shift: in compact key space all valid keys share mask=const, which
// cancels in the normalization; |s| <= ~1.2 so exp2 is overflow-safe. Only the
// tail-pad entries of the LAST tile carry -inf (exp2 -> exact 0).
#define LOG2E      1.4426950408889634f
#define QSCALE     (0.125f * LOG2E)
#define MASK_OFF   (-1.4427e9f)

static __device__ __forceinline__ u16 f2bf(float x) {
    union { float f; unsigned int u; } v; v.f = x;
    unsigned int r = v.u + 0x7fff + ((v.u >> 16) & 1);
    return (u16)(r >> 16);
}
static __device__ __forceinline__ float bf2f(u16 h) {
    union { unsigned int u; float f; } v; v.u = ((unsigned int)h) << 16;
    return v.f;
}
static __device__ __forceinline__ unsigned int cvtpk(float lo, float hi) {
    unsigned int r;
    asm volatile("v_cvt_pk_bf16_f32 %0, %1, %2" : "=v"(r) : "v"(lo), "v"(hi));
    return r;
}
static __device__ __forceinline__ float exp2f_fast(float x) {
    float r; asm volatile("v_exp_f32 %0, %1" : "=v"(r) : "v"(x)); return r;
}
static __device__ __forceinline__ void gload_lds16(const void* g, void* l) {
    __builtin_amdgcn_global_load_lds(
        (const __attribute__((address_space(1))) unsigned int*)g,
        (__attribute__((address_space(3))) unsigned int*)l, 16, 0, 0);
}

// ---------------- fused prep: LN1 (wave/row) + mask scan + rope tables + weight converts ----------------
__global__ void prep_kernel(const float* __restrict__ x, u16* __restrict__ h1,
                            const float* __restrict__ gammas, const float* __restrict__ betas,
                            const float* __restrict__ wq, const float* __restrict__ wk,
                            const float* __restrict__ wv, const float* __restrict__ wo,
                            const float* __restrict__ w1, const float* __restrict__ w2,
                            u16* __restrict__ wqkvT, u16* __restrict__ woT,
                            u16* __restrict__ w1T, u16* __restrict__ w2T,
                            const int* __restrict__ mask, float* __restrict__ maskc,
                            int* __restrict__ invidx, int* __restrict__ nkp,
                            int* __restrict__ ccnt,
                            float* __restrict__ ct, float* __restrict__ st) {
    __shared__ float smem[1056];
    int b = blockIdx.x;
    int t = threadIdx.x;
    if (b < SEQ / 4) {                          // LN1: 4 rows/block, one wave each, no LDS
        int wv_ = t >> 6, lane = t & 63;
        int row = b * 4 + wv_;
        const float* xr = x + (size_t)row * DIM + lane * 8;
        float4 a0 = *(const float4*)xr;
        float4 a1 = *(const float4*)(xr + 4);
        float f[8] = {a0.x, a0.y, a0.z, a0.w, a1.x, a1.y, a1.z, a1.w};
        float s = 0.f, qs = 0.f;
#pragma unroll
        for (int i = 0; i < 8; i++) { s += f[i]; qs += f[i] * f[i]; }
#pragma unroll
        for (int o = 1; o < 64; o <<= 1) {
            s  += __shfl_xor(s, o, 64);
            qs += __shfl_xor(qs, o, 64);
        }
        float mean = s / DIM;
        float var  = qs / DIM - mean * mean;
        float rstd = rsqrtf(var + 1e-5f);
        float g = gammas[0], be = betas[0];
        u16x8 res;
#pragma unroll
        for (int i = 0; i < 8; i += 2) {
            unsigned int pk = cvtpk(g * ((f[i] - mean) * rstd) + be,
                                    g * ((f[i + 1] - mean) * rstd) + be);
            res[i]     = (u16)(pk & 0xffff);
            res[i + 1] = (u16)(pk >> 16);
        }
        *(u16x8*)(h1 + (size_t)row * DIM + lane * 8) = res;
        return;
    }
    b -= SEQ / 4;
    if (b < 1) {                                // mask-compaction scan + counter zeroing
        __shared__ int cnt[256];
        ccnt[t] = 0;                            // zero the 256 split-completion counters
        int base = t * 16;
        int loc[16]; int c = 0;
#pragma unroll
        for (int i = 0; i < 16; i++) { loc[i] = mask[base + i]; c += (loc[i] != 0); }
        cnt[t] = c;
        __syncthreads();
        for (int o = 1; o < 256; o <<= 1) {
            int v = (t >= o) ? cnt[t - o] : 0;
            __syncthreads();
            cnt[t] += v;
            __syncthreads();
        }
        int pos = cnt[t] - c;                   // exclusive prefix
        int total = cnt[255];
#pragma unroll
        for (int i = 0; i < 16; i++)
            invidx[base + i] = loc[i] ? pos++ : -1;
#pragma unroll
        for (int i = 0; i < 16; i++)
            maskc[base + i] = (base + i < total) ? 0.0f : MASK_OFF;
        if (t == 0) *nkp = total;
        return;
    }
    b -= 1;
    if (b < 256) {                              // rope cos/sin tables: [s][i], i<16
        int idx = b * 256 + t;                  // 65536 = 4096*16
        int s = idx >> 4, i = idx & 15;
        float invf = expf(-(float)i * (9.2103403719761836f / 16.0f));  // 10000^(-i/16)
        float freq = (float)s * invf;
        ct[idx] = cosf(freq);
        st[idx] = sinf(freq);
        return;
    }
    b -= 256;
    const float* src; u16* dst; int K, N; float scale = 1.f;
    if (b < 256)       { src = wq; dst = wqkvT;            K = 512;  N = 512; scale = QSCALE; }
    else if (b < 512)  { src = wk; dst = wqkvT + 512*512;  K = 512;  N = 512; b -= 256; }
    else if (b < 768)  { src = wv; dst = wqkvT + 1024*512; K = 512;  N = 512; b -= 512; }
    else if (b < 1024) { src = wo; dst = woT;              K = 512;  N = 512; b -= 768; }
    else if (b < 2048) { src = w1; dst = w1T;              K = 512;  N = 2048; b -= 1024; }
    else               { src = w2; dst = w2T;              K = 2048; N = 512;  b -= 2048; }
    float (*tile)[33] = (float(*)[33])smem;
    int tiles_x = N / 32;
    int n0 = (b % tiles_x) * 32, k0 = (b / tiles_x) * 32;
    int tx = t & 31, ty = t >> 5;               // 32 x 8
#pragma unroll
    for (int i = 0; i < 4; i++) {
        int kk = ty + i * 8;
        tile[kk][tx] = src[(size_t)(k0 + kk) * N + n0 + tx];
    }
    __syncthreads();
#pragma unroll
    for (int i = 0; i < 4; i++) {
        int nn = ty + i * 8;
        dst[(size_t)(n0 + nn) * K + k0 + tx] = f2bf(scale * tile[tx][nn]);
    }
}

// ---------------- LayerNorm LN2, bf16 in/out, wave-per-row ----------------
__global__ void ln_bf16_kernel(const u16* __restrict__ x, u16* __restrict__ out,
                               const float* __restrict__ gammas, const float* __restrict__ betas,
                               int gi) {
    int t = threadIdx.x;
    int wv_ = t >> 6, lane = t & 63;
    int row = blockIdx.x * 4 + wv_;
    u16x8 v = *(const u16x8*)(x + (size_t)row * DIM + lane * 8);
    float f[8];
    float s = 0.f, qs = 0.f;
#pragma unroll
    for (int i = 0; i < 8; i++) { f[i] = bf2f(v[i]); s += f[i]; qs += f[i] * f[i]; }
#pragma unroll
    for (int o = 1; o < 64; o <<= 1) {
        s  += __shfl_xor(s, o, 64);
        qs += __shfl_xor(qs, o, 64);
    }
    float mean = s / DIM;
    float var  = qs / DIM - mean * mean;
    float rstd = rsqrtf(var + 1e-5f);
    float g = gammas[gi], be = betas[gi];
    u16x8 res;
#pragma unroll
    for (int i = 0; i < 8; i += 2) {
        unsigned int pk = cvtpk(g * ((f[i] - mean) * rstd) + be,
                                g * ((f[i + 1] - mean) * rstd) + be);
        res[i]     = (u16)(pk & 0xffff);
        res[i + 1] = (u16)(pk >> 16);
    }
    *(u16x8*)(out + (size_t)row * DIM + lane * 8) = res;
}

constexpr int FLAG_BF16 = 1, FLAG_GELU = 2, FLAG_SPLIT = 4, FLAG_ROPE = 8, FLAG_RESID_BF16 = 16;

// ---------------- bf16 MFMA GEMM, 64-wide tiles, BK=128 (wo / w2): C = A @ WT^T ----------------
template<int MF>
__global__ __launch_bounds__(256) void gemm_bf16(
    const u16* __restrict__ A, const u16* __restrict__ WT,
    const float* __restrict__ bias, const void* __restrict__ resid,
    void* __restrict__ Cq, int M, int N, int K, int flags)
{
    constexpr int BM = MF * 64;
    __shared__ __align__(16) u16 At[2][BM * 128];
    __shared__ __align__(16) u16 Bt[2][64 * 128];
    const int t = threadIdx.x, lane = t & 63, w = t >> 6;
    const int n0 = blockIdx.x * 64, m0 = blockIdx.y * BM;
    const int l15 = lane & 15, l4 = lane >> 4;

    f32x4 acc[MF][4];
#pragma unroll
    for (int m = 0; m < MF; m++)
#pragma unroll
        for (int n = 0; n < 4; n++) acc[m][n] = (f32x4){0.f, 0.f, 0.f, 0.f};

    auto stage = [&](int buf, int k0) {
#pragma unroll
        for (int i = 0; i < MF * 4; i++) {       // A: BM rows x 16 chunks
            int c = (w * MF * 4 + i) * 64 + lane;
            int r = c >> 4, jj = (c & 15) ^ (r & 7);
            gload_lds16(A + (size_t)(m0 + r) * K + k0 + jj * 8,
                        (char*)At[buf] + (w * MF * 4 + i) * 1024);
        }
#pragma unroll
        for (int i = 0; i < 4; i++) {            // B: 64 rows x 16 chunks
            int c = (w * 4 + i) * 64 + lane;
            int r = c >> 4, jj = (c & 15) ^ (r & 7);
            gload_lds16(WT + (size_t)(n0 + r) * K + k0 + jj * 8,
                        (char*)Bt[buf] + (w * 4 + i) * 1024);
        }
    };

    const int NT = K / 128;
    stage(0, 0);
    for (int ti = 0; ti < NT; ti++) {
        const int cur = ti & 1;
        asm volatile("s_waitcnt vmcnt(0)" ::: "memory");
        __syncthreads();
        if (ti + 1 < NT) stage(cur ^ 1, (ti + 1) * 128);
        __builtin_amdgcn_s_setprio(1);
#pragma unroll
        for (int kk = 0; kk < 4; kk++) {
            bf16x8 af[MF], bfr[4];
#pragma unroll
            for (int m = 0; m < MF; m++) {
                int row = w * MF * 16 + m * 16 + l15;
                af[m] = *(bf16x8*)((char*)At[cur] + row * 256 +
                                   ((kk * 64 + l4 * 16) ^ ((row & 7) << 4)));
            }
#pragma unroll
            for (int n = 0; n < 4; n++) {
                int row = n * 16 + l15;
                bfr[n] = *(bf16x8*)((char*)Bt[cur] + row * 256 +
                                    ((kk * 64 + l4 * 16) ^ ((row & 7) << 4)));
            }
#pragma unroll
            for (int m = 0; m < MF; m++)
#pragma unroll
                for (int n = 0; n < 4; n++)
                    acc[m][n] = __builtin_amdgcn_mfma_f32_16x16x32_bf16(
                        af[m], bfr[n], acc[m][n], 0, 0, 0);
        }
        __builtin_amdgcn_s_setprio(0);
    }

#pragma unroll
    for (int m = 0; m < MF; m++)
#pragma unroll
        for (int rr = 0; rr < 4; rr++) {
            int row = m0 + w * MF * 16 + m * 16 + l4 * 4 + rr;
#pragma unroll
            for (int n = 0; n < 4; n++) {
                int colg = n0 + n * 16 + l15;
                float cv = acc[m][n][rr];
                if (bias) cv += bias[colg];
                if (flags & FLAG_GELU) cv = 0.5f * cv * (1.0f + erff(cv * 0.70710678118f));
                if (resid) {
                    if (flags & FLAG_RESID_BF16)
                        cv += bf2f(((const u16*)resid)[(size_t)row * N + colg]);
                    else
                        cv += ((const float*)resid)[(size_t)row * N + colg];
                }
                if (flags & FLAG_BF16) {
                    ((u16*)Cq)[(size_t)row * N + colg] = f2bf(cv);
                } else {
                    ((float*)Cq)[(size_t)row * N + colg] = cv;
                }
            }
        }
}

// ---------------- bf16 MFMA GEMM, 128x128 tile (qkv / ffn1); K/V scattered compacted ----------------
__global__ __launch_bounds__(256) void gemm128(
    const u16* __restrict__ A, const u16* __restrict__ WT,
    const float* __restrict__ bias,
    void* __restrict__ Cq, void* __restrict__ Ck, void* __restrict__ Cv,
    const float* __restrict__ ct, const float* __restrict__ st,
    const int* __restrict__ invidx,
    int M, int N, int K, int flags)
{
    __shared__ __align__(16) u16 At[2][128 * 64];   // 16 KB per buf, swizzled image
    __shared__ __align__(16) u16 Bt[2][128 * 64];
    const int t = threadIdx.x, lane = t & 63, w = t >> 6;
    const int wm = w >> 1, wn = w & 1;
    const int n0 = blockIdx.x * 128, m0 = blockIdx.y * 128;
    const int l15 = lane & 15, l4 = lane >> 4;

    f32x4 acc[4][4];
#pragma unroll
    for (int m = 0; m < 4; m++)
#pragma unroll
        for (int n = 0; n < 4; n++) acc[m][n] = (f32x4){0.f, 0.f, 0.f, 0.f};

    auto stage = [&](int buf, int k0) {
#pragma unroll
        for (int i = 0; i < 4; i++) {
            int c = (w * 4 + i) * 64 + lane;
            int r = c >> 3, j = (c & 7) ^ (r & 7);
            gload_lds16(A + (size_t)(m0 + r) * K + k0 + j * 8,
                        (char*)At[buf] + (w * 4 + i) * 1024);
            gload_lds16(WT + (size_t)(n0 + r) * K + k0 + j * 8,
                        (char*)Bt[buf] + (w * 4 + i) * 1024);
        }
    };

    const int NT = K / 64;
    stage(0, 0);
    for (int ti = 0; ti < NT; ti++) {
        const int cur = ti & 1;
        asm volatile("s_waitcnt vmcnt(0)" ::: "memory");
        __syncthreads();
        if (ti + 1 < NT) stage(cur ^ 1, (ti + 1) * 64);
        __builtin_amdgcn_s_setprio(1);
#pragma unroll
        for (int kk = 0; kk < 2; kk++) {
            bf16x8 af[4], bfr[4];
#pragma unroll
            for (int m = 0; m < 4; m++) {
                int row = wm * 64 + m * 16 + l15;
                af[m] = *(bf16x8*)((char*)At[cur] + row * 128 +
                                   ((kk * 64 + l4 * 16) ^ ((row & 7) << 4)));
            }
#pragma unroll
            for (int n = 0; n < 4; n++) {
                int row = wn * 64 + n * 16 + l15;
                bfr[n] = *(bf16x8*)((char*)Bt[cur] + row * 128 +
                                    ((kk * 64 + l4 * 16) ^ ((row & 7) << 4)));
            }
#pragma unroll
            for (int m = 0; m < 4; m++)
#pragma unroll
                for (int n = 0; n < 4; n++)
                    acc[m][n] = __builtin_amdgcn_mfma_f32_16x16x32_bf16(
                        af[m], bfr[n], acc[m][n], 0, 0, 0);
        }
        __builtin_amdgcn_s_setprio(0);
    }

    // epilogue (bias / rope / gelu / split-with-compaction / bf16)
    const int which = (n0 + wn * 64) >> 9;      // constant per wave
#pragma unroll
    for (int m = 0; m < 4; m++)
#pragma unroll
        for (int rr = 0; rr < 4; rr++) {
            int row = m0 + wm * 64 + m * 16 + l4 * 4 + rr;
            int orow = row;
            if ((flags & FLAG_SPLIT) && which > 0) orow = invidx[row];  // K/V: compact slot
#pragma unroll
            for (int n = 0; n < 4; n++) {
                int colg = n0 + wn * 64 + n * 16 + l15;
                float cv = acc[m][n][rr];
                if (bias) cv += bias[colg];
                // fused RoPE for q/k sections (original row's tables, pre-scatter)
                if ((flags & FLAG_ROPE) && which < 2 && n < 2) {
                    float partner = __shfl_xor(cv, 1, 64);
                    int i = (n * 16 + l15) >> 1;
                    float cc = ct[row * 16 + i], ss = st[row * 16 + i];
                    cv = (l15 & 1) ? (cv * cc + partner * ss) : (cv * cc - partner * ss);
                }
                if (flags & FLAG_GELU) cv = 0.5f * cv * (1.0f + erff(cv * 0.70710678118f));
                if (flags & FLAG_SPLIT) {
                    if (orow >= 0) {
                        u16* dst = which == 0 ? (u16*)Cq : which == 1 ? (u16*)Ck : (u16*)Cv;
                        dst[(size_t)orow * 512 + (colg & 511)] = f2bf(cv);
                    }
                } else {
                    ((u16*)Cq)[(size_t)row * N + colg] = f2bf(cv);
                }
            }
        }
}

// ---------------- per-head transpose of compacted V: vc (nk, NH*HD) -> vTc (NH, HD, SEQ) ----------------
__global__ void transpose_c(const u16* __restrict__ vc, const int* __restrict__ nkp,
                            u16* __restrict__ vTc) {
    int nk = *nkp;
    int s0 = blockIdx.x * 64;
    if (s0 >= ((nk + 63) & ~63)) return;        // past last compacted tile
    __shared__ __align__(16) u16 tile[64][80];
    int h = blockIdx.y;
    int t = threadIdx.x;               // 256
#pragma unroll
    for (int p = 0; p < 2; p++) {
        int c = p * 256 + t;
        int r = c >> 3, j = c & 7;
        u16x8 vv = {};
        if (s0 + r < nk)
            vv = *(const u16x8*)(vc + (size_t)(s0 + r) * DIM + h * HDIM + j * 8);
        *(u16x8*)&tile[r][j * 8] = vv;
    }
    __syncthreads();
#pragma unroll
    for (int p = 0; p < 2; p++) {
        int c = p * 256 + t;
        int d = c >> 3, j = c & 7;
        u16x8 vv;
#pragma unroll
        for (int i = 0; i < 8; i++) vv[i] = tile[j * 8 + i][d];
        *(u16x8*)(vTc + ((size_t)h * HDIM + d) * SEQ + s0 + j * 8) = vv;
    }
}

// ---------------- flash attention over COMPACTED keys + FUSED split combine ----------------
// 32 q/wave, KV-split x3, LDS-P, no-shift exp2 softmax, ones-MFMA row sums.
// After writing partials, blocks release (threadfence) and bump a per-(h,q0)
// counter; the LAST split block acquires and combines (O0+O1+O2)/(l0+l1+l2)
// for its head's 64 cols — deterministic (fixed split read order).
__global__ __launch_bounds__(256, 3) void fattn_kernel(
    const u16* __restrict__ q, const u16* __restrict__ k,
    const u16* __restrict__ vT, const float* __restrict__ maskc,
    const int* __restrict__ nkp,
    u16* __restrict__ Opart, float* __restrict__ lpart,
    int* __restrict__ ccnt, u16* __restrict__ attnb)
{
    __shared__ __align__(16) u16 k_s[2][64 * 64];     // 16 KB [buf][key][d] swizzled image
    __shared__ __align__(16) u16 vt_s[2][64 * 64];    // 16 KB [buf][d][key] swizzled image
    __shared__ __align__(16) u16 p_s[4][32 * 64];     // 16 KB per-wave [q][key] swizzled

    const int t = threadIdx.x;
    const int lane = t & 63;
    const int w = t >> 6;
    const int h = blockIdx.x;
    const int q0 = blockIdx.y * 128;
    const int split = blockIdx.z;
    const int nk = *nkp;
    const int ntiles = (nk + 63) >> 6;
    const int tstart = (split * ntiles) / 3;
    const int tend   = ((split + 1) * ntiles) / 3;
    const int l15 = lane & 15, g = lane >> 4;

    // Q as B-frags, straight from global: q-row = q0+w*32+qh*16+l15, d = g*8+j (+32)
    bf16x8 qf[2][2];
#pragma unroll
    for (int qh = 0; qh < 2; qh++) {
        const u16* qrow = q + (size_t)(q0 + w * 32 + qh * 16 + l15) * DIM + h * HDIM;
        qf[qh][0] = *(const bf16x8*)(qrow + g * 8);
        qf[qh][1] = *(const bf16x8*)(qrow + g * 8 + 32);
    }

    // ones A-fragment (bf16 1.0 = 0x3F80) for the row-sum MFMA
    const bf16x8 ones = (bf16x8){16256, 16256, 16256, 16256, 16256, 16256, 16256, 16256};

    f32x4 O[2][4];                    // O^T: [qh][dt], reg r -> d = dt*16+4g+r, col q
    f32x4 lacc[2];                    // row-sum accumulator (all regs equal)
#pragma unroll
    for (int qh = 0; qh < 2; qh++) {
#pragma unroll
        for (int dt = 0; dt < 4; dt++) O[qh][dt] = (f32x4){0.f, 0.f, 0.f, 0.f};
        lacc[qh] = (f32x4){0.f, 0.f, 0.f, 0.f};
    }

    char* pbase = (char*)p_s[w];
    const int psw = (l15 & 7) << 4;

    auto stage = [&](int buf, int kb2) {
#pragma unroll
        for (int i = 0; i < 2; i++) {
            int c = (w * 2 + i) * 64 + lane;
            int r = c >> 3, j = (c & 7) ^ (r & 7);
            gload_lds16(k + (size_t)(kb2 + r) * DIM + h * HDIM + j * 8,
                        (char*)k_s + buf * 8192 + (w * 2 + i) * 1024);
            gload_lds16(vT + ((size_t)h * HDIM + r) * SEQ + kb2 + j * 8,
                        (char*)vt_s + buf * 8192 + (w * 2 + i) * 1024);
        }
    };

    if (tstart < tend) stage(0, tstart * 64);
    for (int ti = tstart; ti < tend; ti++) {
        const int cur = (ti - tstart) & 1;
        const int kb = ti * 64;
        asm volatile("s_waitcnt vmcnt(0)" ::: "memory");
        __syncthreads();
        if (ti + 1 < tend) stage(cur ^ 1, kb + 64);

        char* kcur = (char*)k_s + cur * 8192;
        char* vcur = (char*)vt_s + cur * 8192;

        // ---- QK^T (swapped): 2 independent chains (qh) off shared K A-frags ----
        f32x4 sacc[2][4];
        __builtin_amdgcn_s_setprio(1);
#pragma unroll
        for (int kt = 0; kt < 4; kt++) {
            int key = kt * 16 + l15;
            int ksw = (key & 7) << 4;
            char* kbase = kcur + key * 128;
            bf16x8 a0 = *(bf16x8*)(kbase + ((g * 16)      ^ ksw));
            bf16x8 a1 = *(bf16x8*)(kbase + ((g * 16 + 64) ^ ksw));
#pragma unroll
            for (int qh = 0; qh < 2; qh++) {
                f32x4 z = (f32x4){0.f, 0.f, 0.f, 0.f};
                z = __builtin_amdgcn_mfma_f32_16x16x32_bf16(a0, qf[qh][0], z, 0, 0, 0);
                z = __builtin_amdgcn_mfma_f32_16x16x32_bf16(a1, qf[qh][1], z, 0, 0, 0);
                sacc[qh][kt] = z;
            }
        }
        __builtin_amdgcn_s_setprio(0);

        // ---- P = exp2(sacc) [+pad mask only on the LAST tile] + b64 pack ----
        const bool haspad = (ti == ntiles - 1);
        if (!haspad) {
#pragma unroll
            for (int qh = 0; qh < 2; qh++)
#pragma unroll
                for (int kt = 0; kt < 4; kt++) {
                    float p0 = exp2f_fast(sacc[qh][kt][0]);
                    float p1 = exp2f_fast(sacc[qh][kt][1]);
                    float p2 = exp2f_fast(sacc[qh][kt][2]);
                    float p3 = exp2f_fast(sacc[qh][kt][3]);
                    uint2 pk;
                    pk.x = cvtpk(p0, p1);
                    pk.y = cvtpk(p2, p3);
                    int colb = (kt * 16 + g * 4) * 2;      // byte col, 8B aligned
                    *(uint2*)(pbase + (qh * 16 + l15) * 128 + (colb ^ psw)) = pk;
                }
        } else {
            float4 mf4[4];
#pragma unroll
            for (int kt = 0; kt < 4; kt++)
                mf4[kt] = *(const float4*)(maskc + kb + kt * 16 + g * 4);
#pragma unroll
            for (int qh = 0; qh < 2; qh++)
#pragma unroll
                for (int kt = 0; kt < 4; kt++) {
                    float p0 = exp2f_fast(sacc[qh][kt][0] + mf4[kt].x);
                    float p1 = exp2f_fast(sacc[qh][kt][1] + mf4[kt].y);
                    float p2 = exp2f_fast(sacc[qh][kt][2] + mf4[kt].z);
                    float p3 = exp2f_fast(sacc[qh][kt][3] + mf4[kt].w);
                    uint2 pk;
                    pk.x = cvtpk(p0, p1);
                    pk.y = cvtpk(p2, p3);
                    int colb = (kt * 16 + g * 4) * 2;
                    *(uint2*)(pbase + (qh * 16 + l15) * 128 + (colb ^ psw)) = pk;
                }
        }

        // ---- PV: O^T += V^T(A) @ P(B); lacc += ones @ P (row sums) ----
        __builtin_amdgcn_s_setprio(1);
#pragma unroll
        for (int h2 = 0; h2 < 2; h2++) {
            bf16x8 pb[2];
#pragma unroll
            for (int qh = 0; qh < 2; qh++)
                pb[qh] = *(bf16x8*)(pbase + (qh * 16 + l15) * 128 +
                                    (((h2 * 4 + g) * 16) ^ psw));
#pragma unroll
            for (int dt = 0; dt < 4; dt++) {
                int d = dt * 16 + l15;
                bf16x8 va = *(bf16x8*)(vcur + d * 128 +
                                       (((h2 * 4 + g) * 16) ^ ((d & 7) << 4)));
#pragma unroll
                for (int qh = 0; qh < 2; qh++)
                    O[qh][dt] = __builtin_amdgcn_mfma_f32_16x16x32_bf16(
                        va, pb[qh], O[qh][dt], 0, 0, 0);
            }
#pragma unroll
            for (int qh = 0; qh < 2; qh++)
                lacc[qh] = __builtin_amdgcn_mfma_f32_16x16x32_bf16(
                    ones, pb[qh], lacc[qh], 0, 0, 0);
        }
        __builtin_amdgcn_s_setprio(0);
    }

    // ---- write unnormalized partial O (bf16) + partial row sums ----
#pragma unroll
    for (int qh = 0; qh < 2; qh++) {
        float lrun = lacc[qh][0];     // every lane holds the full sum for its q-col
        int row = q0 + w * 32 + qh * 16 + l15;
        u16* orow = Opart + (size_t)split * SEQ * DIM + (size_t)row * DIM + h * HDIM;
#pragma unroll
        for (int dt = 0; dt < 4; dt++)
#pragma unroll
            for (int r = 0; r < 4; r += 2) {
                unsigned int pk = cvtpk(O[qh][dt][r], O[qh][dt][r + 1]);
                *(unsigned int*)(orow + dt * 16 + 4 * g + r) = pk;
            }
        if (g == 0)
            lpart[((size_t)split * NH + h) * SEQ + row] = lrun;
    }

    // ---- fused combine: last split block for this (h, q0) finishes the job ----
    __threadfence();                               // release partials (device scope)
    __syncthreads();                               // all waves' fences done
    __shared__ int lastFlag;
    if (t == 0) {
        int prev = atomicAdd(&ccnt[h * (SEQ / 128) + blockIdx.y], 1);
        lastFlag = (prev == KSPLIT - 1);
    }
    __syncthreads();
    if (!lastFlag) return;
    __threadfence();                               // acquire others' partials
    {
        int row = q0 + (t >> 1);
        int col = h * HDIM + (t & 1) * 32;         // each thread: 32 cols = 4 u16x8
        float l = lpart[((size_t)0 * NH + h) * SEQ + row]
                + lpart[((size_t)1 * NH + h) * SEQ + row]
                + lpart[((size_t)2 * NH + h) * SEQ + row];
        float inv = 1.0f / l;
        const size_t SD = (size_t)SEQ * DIM;
        const u16* base = Opart + (size_t)row * DIM + col;
#pragma unroll
        for (int chunk = 0; chunk < 4; chunk++) {
            u16x8 ua = *(const u16x8*)(base + chunk * 8);
            u16x8 ub = *(const u16x8*)(base + SD + chunk * 8);
            u16x8 uc = *(const u16x8*)(base + 2 * SD + chunk * 8);
            u16x8 res;
#pragma unroll
            for (int j = 0; j < 8; j += 2) {
                float o0 = bf2f(ua[j])     + bf2f(ub[j])     + bf2f(uc[j]);
                float o1 = bf2f(ua[j + 1]) + bf2f(ub[j + 1]) + bf2f(uc[j + 1]);
                unsigned int pk = cvtpk(o0 * inv, o1 * inv);
                res[j]     = (u16)(pk & 0xffff);
                res[j + 1] = (u16)(pk >> 16);
            }
            *(u16x8*)(attnb + (size_t)row * DIM + col + chunk * 8) = res;
        }
    }
}

extern "C" void kernel_launch(void* const* d_in, const int* in_sizes, int n_in,
                              void* d_out, int out_size, void* d_ws, size_t ws_size,
                              hipStream_t stream) {
    const float* x      = (const float*)d_in[0];
    const float* gammas = (const float*)d_in[1];
    const float* betas  = (const float*)d_in[2];
    const float* wq     = (const float*)d_in[3];
    const float* wk     = (const float*)d_in[4];
    const float* wv     = (const float*)d_in[5];
    const float* wo     = (const float*)d_in[6];
    const float* bo     = (const float*)d_in[7];
    const float* w1     = (const float*)d_in[8];
    const float* b1     = (const float*)d_in[9];
    const float* w2     = (const float*)d_in[10];
    const float* b2     = (const float*)d_in[11];
    const int*   mask   = (const int*)d_in[12];
    float* out = (float*)d_out;

    // ---- workspace layout (bytes); peak ~41 MB ----
    char* wsb = (char*)d_ws;
    u16*   h1b   = (u16*)(wsb + 0);                 // 4 MB; LN1 out; then attnb/f1b
    u16*   kc    = (u16*)(wsb + (4ull  << 20));     // 4 MB compacted K (qkv epilogue scatter)
    u16*   vc    = (u16*)(wsb + (8ull  << 20));     // 4 MB compacted V
    u16*   vTc   = (u16*)(wsb + (12ull << 20));     // 4 MB compacted V^T
    u16*   qb    = (u16*)(wsb + (16ull << 20));     // 4 MB; reused as h2b
    u16*   Opart = (u16*)(wsb + (20ull << 20));     // 12 MB: 3 splits x 4 MB (20-32)
    u16*   x2b   = (u16*)(wsb + (20ull << 20));     // 4 MB bf16 x2 (over dead Opart)
    u16*   wqkvT = (u16*)(wsb + (32ull << 20));     // 1.5 MB
    u16*   woT   = wqkvT + 1536 * 512;              // 0.5 MB
    u16*   w1T   = woT   + 512 * 512;               // 2 MB
    u16*   w2T   = w1T   + 2048 * 512;              // 2 MB (ends 38 MB)
    float* maskc = (float*)(wsb + (38ull << 20));   // 16 KB
    int*   invidx= (int*)(wsb + (38ull << 20) + (64 << 10));   // 16 KB
    int*   nkp   = (int*)(wsb + (38ull << 20) + (128 << 10));  // 4 B
    float* ct    = (float*)(wsb + (39ull << 20));   // 256 KB
    float* st    = ct + 65536;                      // 256 KB
    float* lpart = (float*)(wsb + (40ull << 20));   // 384 KB
    int*   ccnt  = (int*)(wsb + (40ull << 20) + (512 << 10));  // 1 KB (256 counters)
    u16*   f1b   = h1b;                             // 16 MB spanning slots 0-3 (FFN phase)
    u16*   h2b   = qb;
    u16*   attnb = h1b;

    // 0. fused prep: LN1 + mask scan (invidx) + counter zero + rope tables + weight converts
    prep_kernel<<<SEQ / 4 + 1 + 256 + 3072, 256, 0, stream>>>(
        x, h1b, gammas, betas, wq, wk, wv, wo, w1, w2,
        wqkvT, woT, w1T, w2T, mask, maskc, invidx, nkp, ccnt, ct, st);
    // 1. fused QKV projection + RoPE; K/V scattered directly to compacted slots
    gemm128<<<dim3(1536 / 128, SEQ / 128), 256, 0, stream>>>(
        h1b, wqkvT, nullptr, qb, kc, vc, ct, st, invidx,
        SEQ, 1536, DIM, FLAG_SPLIT | FLAG_BF16 | FLAG_ROPE);
    // 2. per-head transpose of compacted V (early-exit past last tile)
    transpose_c<<<dim3(SEQ / 64, NH), 256, 0, stream>>>(vc, nkp, vTc);
    // 3. attention over compacted keys, KV-split x3, FUSED combine (no separate launch)
    fattn_kernel<<<dim3(NH, SEQ / 128, KSPLIT), 256, 0, stream>>>(
        qb, kc, vTc, maskc, nkp, Opart, lpart, ccnt, attnb);
    // 4. x2 = bf16(x + attn@wo + bo)  [x2b over dead Opart], BK=128
    gemm_bf16<1><<<dim3(DIM / 64, SEQ / 64), 256, 0, stream>>>(
        attnb, woT, bo, (const void*)x, x2b, SEQ, DIM, DIM, FLAG_BF16);
    // 5. h2 = LN(x2b) (bf16 in/out, wave-per-row)
    ln_bf16_kernel<<<SEQ / 4, 256, 0, stream>>>(x2b, h2b, gammas, betas, 1);
    // 6. f1 = gelu(h2@w1 + b1) (bf16), 128x128 tiles
    gemm128<<<dim3(FFD / 128, SEQ / 128), 256, 0, stream>>>(
        h2b, w1T, b1, f1b, nullptr, nullptr, nullptr, nullptr, nullptr,
        SEQ, FFD, DIM, FLAG_BF16 | FLAG_GELU);
    // 7. out = x2b + f1@w2 + b2 (f32 out, bf16 resid), BK=128
    gemm_bf16<1><<<dim3(DIM / 64, SEQ / 64), 256, 0, stream>>>(
        f1b, w2T, b2, (const void*)x2b, out, SEQ, DIM, FFD, FLAG_RESID_BF16);
}

// Round 20
// 149.214 us; speedup vs baseline: 1.7940x; 1.7940x over previous
//
#include <hip/hip_runtime.h>
#include <math.h>

constexpr int SEQ  = 4096;
constexpr int DIM  = 512;
constexpr int NH   = 8;
constexpr int HDIM = 64;
constexpr int FFD  = 2048;
constexpr int KSPLIT = 3;

typedef unsigned short u16;
typedef __attribute__((ext_vector_type(8))) short bf16x8;
typedef __attribute__((ext_vector_type(4))) float f32x4;
typedef __attribute__((ext_vector_type(8))) unsigned short u16x8;

// score scale: (1/8) * log2(e), folded into wq. Softmax computed in exp2 domain.
// NO static shift: in compact key space all valid keys share mask=const, which
// cancels in the normalization; |s| <= ~1.2 so exp2 is overflow-safe. Only the
// tail-pad entries of the LAST tile carry -inf (exp2 -> exact 0).
#define LOG2E      1.4426950408889634f
#define QSCALE     (0.125f * LOG2E)
#define MASK_OFF   (-1.4427e9f)

static __device__ __forceinline__ u16 f2bf(float x) {
    union { float f; unsigned int u; } v; v.f = x;
    unsigned int r = v.u + 0x7fff + ((v.u >> 16) & 1);
    return (u16)(r >> 16);
}
static __device__ __forceinline__ float bf2f(u16 h) {
    union { unsigned int u; float f; } v; v.u = ((unsigned int)h) << 16;
    return v.f;
}
static __device__ __forceinline__ unsigned int cvtpk(float lo, float hi) {
    unsigned int r;
    asm volatile("v_cvt_pk_bf16_f32 %0, %1, %2" : "=v"(r) : "v"(lo), "v"(hi));
    return r;
}
static __device__ __forceinline__ float exp2f_fast(float x) {
    float r; asm volatile("v_exp_f32 %0, %1" : "=v"(r) : "v"(x)); return r;
}
static __device__ __forceinline__ void gload_lds16(const void* g, void* l) {
    __builtin_amdgcn_global_load_lds(
        (const __attribute__((address_space(1))) unsigned int*)g,
        (__attribute__((address_space(3))) unsigned int*)l, 16, 0, 0);
}

// ---------------- fused prep: LN1 (wave/row) + mask scan + rope tables + weight converts ----------------
__global__ void prep_kernel(const float* __restrict__ x, u16* __restrict__ h1,
                            const float* __restrict__ gammas, const float* __restrict__ betas,
                            const float* __restrict__ wq, const float* __restrict__ wk,
                            const float* __restrict__ wv, const float* __restrict__ wo,
                            const float* __restrict__ w1, const float* __restrict__ w2,
                            u16* __restrict__ wqkvT, u16* __restrict__ woT,
                            u16* __restrict__ w1T, u16* __restrict__ w2T,
                            const int* __restrict__ mask, float* __restrict__ maskc,
                            int* __restrict__ invidx, int* __restrict__ nkp,
                            float* __restrict__ ct, float* __restrict__ st) {
    __shared__ float smem[1056];
    int b = blockIdx.x;
    int t = threadIdx.x;
    if (b < SEQ / 4) {                          // LN1: 4 rows/block, one wave each, no LDS
        int wv_ = t >> 6, lane = t & 63;
        int row = b * 4 + wv_;
        const float* xr = x + (size_t)row * DIM + lane * 8;
        float4 a0 = *(const float4*)xr;
        float4 a1 = *(const float4*)(xr + 4);
        float f[8] = {a0.x, a0.y, a0.z, a0.w, a1.x, a1.y, a1.z, a1.w};
        float s = 0.f, qs = 0.f;
#pragma unroll
        for (int i = 0; i < 8; i++) { s += f[i]; qs += f[i] * f[i]; }
#pragma unroll
        for (int o = 1; o < 64; o <<= 1) {
            s  += __shfl_xor(s, o, 64);
            qs += __shfl_xor(qs, o, 64);
        }
        float mean = s / DIM;
        float var  = qs / DIM - mean * mean;
        float rstd = rsqrtf(var + 1e-5f);
        float g = gammas[0], be = betas[0];
        u16x8 res;
#pragma unroll
        for (int i = 0; i < 8; i += 2) {
            unsigned int pk = cvtpk(g * ((f[i] - mean) * rstd) + be,
                                    g * ((f[i + 1] - mean) * rstd) + be);
            res[i]     = (u16)(pk & 0xffff);
            res[i + 1] = (u16)(pk >> 16);
        }
        *(u16x8*)(h1 + (size_t)row * DIM + lane * 8) = res;
        return;
    }
    b -= SEQ / 4;
    if (b < 1) {                                // mask-compaction scan (1 block, 256 thr x 16)
        __shared__ int cnt[256];
        int base = t * 16;
        int loc[16]; int c = 0;
#pragma unroll
        for (int i = 0; i < 16; i++) { loc[i] = mask[base + i]; c += (loc[i] != 0); }
        cnt[t] = c;
        __syncthreads();
        for (int o = 1; o < 256; o <<= 1) {
            int v = (t >= o) ? cnt[t - o] : 0;
            __syncthreads();
            cnt[t] += v;
            __syncthreads();
        }
        int pos = cnt[t] - c;                   // exclusive prefix
        int total = cnt[255];
#pragma unroll
        for (int i = 0; i < 16; i++)
            invidx[base + i] = loc[i] ? pos++ : -1;
#pragma unroll
        for (int i = 0; i < 16; i++)
            maskc[base + i] = (base + i < total) ? 0.0f : MASK_OFF;
        if (t == 0) *nkp = total;
        return;
    }
    b -= 1;
    if (b < 256) {                              // rope cos/sin tables: [s][i], i<16
        int idx = b * 256 + t;                  // 65536 = 4096*16
        int s = idx >> 4, i = idx & 15;
        float invf = expf(-(float)i * (9.2103403719761836f / 16.0f));  // 10000^(-i/16)
        float freq = (float)s * invf;
        ct[idx] = cosf(freq);
        st[idx] = sinf(freq);
        return;
    }
    b -= 256;
    const float* src; u16* dst; int K, N; float scale = 1.f;
    if (b < 256)       { src = wq; dst = wqkvT;            K = 512;  N = 512; scale = QSCALE; }
    else if (b < 512)  { src = wk; dst = wqkvT + 512*512;  K = 512;  N = 512; b -= 256; }
    else if (b < 768)  { src = wv; dst = wqkvT + 1024*512; K = 512;  N = 512; b -= 512; }
    else if (b < 1024) { src = wo; dst = woT;              K = 512;  N = 512; b -= 768; }
    else if (b < 2048) { src = w1; dst = w1T;              K = 512;  N = 2048; b -= 1024; }
    else               { src = w2; dst = w2T;              K = 2048; N = 512;  b -= 2048; }
    float (*tile)[33] = (float(*)[33])smem;
    int tiles_x = N / 32;
    int n0 = (b % tiles_x) * 32, k0 = (b / tiles_x) * 32;
    int tx = t & 31, ty = t >> 5;               // 32 x 8
#pragma unroll
    for (int i = 0; i < 4; i++) {
        int kk = ty + i * 8;
        tile[kk][tx] = src[(size_t)(k0 + kk) * N + n0 + tx];
    }
    __syncthreads();
#pragma unroll
    for (int i = 0; i < 4; i++) {
        int nn = ty + i * 8;
        dst[(size_t)(n0 + nn) * K + k0 + tx] = f2bf(scale * tile[tx][nn]);
    }
}

// ---------------- LayerNorm LN2, bf16 in/out, wave-per-row ----------------
__global__ void ln_bf16_kernel(const u16* __restrict__ x, u16* __restrict__ out,
                               const float* __restrict__ gammas, const float* __restrict__ betas,
                               int gi) {
    int t = threadIdx.x;
    int wv_ = t >> 6, lane = t & 63;
    int row = blockIdx.x * 4 + wv_;
    u16x8 v = *(const u16x8*)(x + (size_t)row * DIM + lane * 8);
    float f[8];
    float s = 0.f, qs = 0.f;
#pragma unroll
    for (int i = 0; i < 8; i++) { f[i] = bf2f(v[i]); s += f[i]; qs += f[i] * f[i]; }
#pragma unroll
    for (int o = 1; o < 64; o <<= 1) {
        s  += __shfl_xor(s, o, 64);
        qs += __shfl_xor(qs, o, 64);
    }
    float mean = s / DIM;
    float var  = qs / DIM - mean * mean;
    float rstd = rsqrtf(var + 1e-5f);
    float g = gammas[gi], be = betas[gi];
    u16x8 res;
#pragma unroll
    for (int i = 0; i < 8; i += 2) {
        unsigned int pk = cvtpk(g * ((f[i] - mean) * rstd) + be,
                                g * ((f[i + 1] - mean) * rstd) + be);
        res[i]     = (u16)(pk & 0xffff);
        res[i + 1] = (u16)(pk >> 16);
    }
    *(u16x8*)(out + (size_t)row * DIM + lane * 8) = res;
}

constexpr int FLAG_BF16 = 1, FLAG_GELU = 2, FLAG_SPLIT = 4, FLAG_ROPE = 8, FLAG_RESID_BF16 = 16;

// ---------------- bf16 MFMA GEMM, 64-wide tiles, BK=128 (wo / w2): C = A @ WT^T ----------------
template<int MF>
__global__ __launch_bounds__(256) void gemm_bf16(
    const u16* __restrict__ A, const u16* __restrict__ WT,
    const float* __restrict__ bias, const void* __restrict__ resid,
    void* __restrict__ Cq, int M, int N, int K, int flags)
{
    constexpr int BM = MF * 64;
    __shared__ __align__(16) u16 At[2][BM * 128];
    __shared__ __align__(16) u16 Bt[2][64 * 128];
    const int t = threadIdx.x, lane = t & 63, w = t >> 6;
    const int n0 = blockIdx.x * 64, m0 = blockIdx.y * BM;
    const int l15 = lane & 15, l4 = lane >> 4;

    f32x4 acc[MF][4];
#pragma unroll
    for (int m = 0; m < MF; m++)
#pragma unroll
        for (int n = 0; n < 4; n++) acc[m][n] = (f32x4){0.f, 0.f, 0.f, 0.f};

    auto stage = [&](int buf, int k0) {
#pragma unroll
        for (int i = 0; i < MF * 4; i++) {       // A: BM rows x 16 chunks
            int c = (w * MF * 4 + i) * 64 + lane;
            int r = c >> 4, jj = (c & 15) ^ (r & 7);
            gload_lds16(A + (size_t)(m0 + r) * K + k0 + jj * 8,
                        (char*)At[buf] + (w * MF * 4 + i) * 1024);
        }
#pragma unroll
        for (int i = 0; i < 4; i++) {            // B: 64 rows x 16 chunks
            int c = (w * 4 + i) * 64 + lane;
            int r = c >> 4, jj = (c & 15) ^ (r & 7);
            gload_lds16(WT + (size_t)(n0 + r) * K + k0 + jj * 8,
                        (char*)Bt[buf] + (w * 4 + i) * 1024);
        }
    };

    const int NT = K / 128;
    stage(0, 0);
    for (int ti = 0; ti < NT; ti++) {
        const int cur = ti & 1;
        asm volatile("s_waitcnt vmcnt(0)" ::: "memory");
        __syncthreads();
        if (ti + 1 < NT) stage(cur ^ 1, (ti + 1) * 128);
        __builtin_amdgcn_s_setprio(1);
#pragma unroll
        for (int kk = 0; kk < 4; kk++) {
            bf16x8 af[MF], bfr[4];
#pragma unroll
            for (int m = 0; m < MF; m++) {
                int row = w * MF * 16 + m * 16 + l15;
                af[m] = *(bf16x8*)((char*)At[cur] + row * 256 +
                                   ((kk * 64 + l4 * 16) ^ ((row & 7) << 4)));
            }
#pragma unroll
            for (int n = 0; n < 4; n++) {
                int row = n * 16 + l15;
                bfr[n] = *(bf16x8*)((char*)Bt[cur] + row * 256 +
                                    ((kk * 64 + l4 * 16) ^ ((row & 7) << 4)));
            }
#pragma unroll
            for (int m = 0; m < MF; m++)
#pragma unroll
                for (int n = 0; n < 4; n++)
                    acc[m][n] = __builtin_amdgcn_mfma_f32_16x16x32_bf16(
                        af[m], bfr[n], acc[m][n], 0, 0, 0);
        }
        __builtin_amdgcn_s_setprio(0);
    }

#pragma unroll
    for (int m = 0; m < MF; m++)
#pragma unroll
        for (int rr = 0; rr < 4; rr++) {
            int row = m0 + w * MF * 16 + m * 16 + l4 * 4 + rr;
#pragma unroll
            for (int n = 0; n < 4; n++) {
                int colg = n0 + n * 16 + l15;
                float cv = acc[m][n][rr];
                if (bias) cv += bias[colg];
                if (flags & FLAG_GELU) cv = 0.5f * cv * (1.0f + erff(cv * 0.70710678118f));
                if (resid) {
                    if (flags & FLAG_RESID_BF16)
                        cv += bf2f(((const u16*)resid)[(size_t)row * N + colg]);
                    else
                        cv += ((const float*)resid)[(size_t)row * N + colg];
                }
                if (flags & FLAG_BF16) {
                    ((u16*)Cq)[(size_t)row * N + colg] = f2bf(cv);
                } else {
                    ((float*)Cq)[(size_t)row * N + colg] = cv;
                }
            }
        }
}

// ---------------- bf16 MFMA GEMM, 128x128 tile (qkv / ffn1); K/V scattered compacted ----------------
__global__ __launch_bounds__(256) void gemm128(
    const u16* __restrict__ A, const u16* __restrict__ WT,
    const float* __restrict__ bias,
    void* __restrict__ Cq, void* __restrict__ Ck, void* __restrict__ Cv,
    const float* __restrict__ ct, const float* __restrict__ st,
    const int* __restrict__ invidx,
    int M, int N, int K, int flags)
{
    __shared__ __align__(16) u16 At[2][128 * 64];   // 16 KB per buf, swizzled image
    __shared__ __align__(16) u16 Bt[2][128 * 64];
    const int t = threadIdx.x, lane = t & 63, w = t >> 6;
    const int wm = w >> 1, wn = w & 1;
    const int n0 = blockIdx.x * 128, m0 = blockIdx.y * 128;
    const int l15 = lane & 15, l4 = lane >> 4;

    f32x4 acc[4][4];
#pragma unroll
    for (int m = 0; m < 4; m++)
#pragma unroll
        for (int n = 0; n < 4; n++) acc[m][n] = (f32x4){0.f, 0.f, 0.f, 0.f};

    auto stage = [&](int buf, int k0) {
#pragma unroll
        for (int i = 0; i < 4; i++) {
            int c = (w * 4 + i) * 64 + lane;
            int r = c >> 3, j = (c & 7) ^ (r & 7);
            gload_lds16(A + (size_t)(m0 + r) * K + k0 + j * 8,
                        (char*)At[buf] + (w * 4 + i) * 1024);
            gload_lds16(WT + (size_t)(n0 + r) * K + k0 + j * 8,
                        (char*)Bt[buf] + (w * 4 + i) * 1024);
        }
    };

    const int NT = K / 64;
    stage(0, 0);
    for (int ti = 0; ti < NT; ti++) {
        const int cur = ti & 1;
        asm volatile("s_waitcnt vmcnt(0)" ::: "memory");
        __syncthreads();
        if (ti + 1 < NT) stage(cur ^ 1, (ti + 1) * 64);
        __builtin_amdgcn_s_setprio(1);
#pragma unroll
        for (int kk = 0; kk < 2; kk++) {
            bf16x8 af[4], bfr[4];
#pragma unroll
            for (int m = 0; m < 4; m++) {
                int row = wm * 64 + m * 16 + l15;
                af[m] = *(bf16x8*)((char*)At[cur] + row * 128 +
                                   ((kk * 64 + l4 * 16) ^ ((row & 7) << 4)));
            }
#pragma unroll
            for (int n = 0; n < 4; n++) {
                int row = wn * 64 + n * 16 + l15;
                bfr[n] = *(bf16x8*)((char*)Bt[cur] + row * 128 +
                                    ((kk * 64 + l4 * 16) ^ ((row & 7) << 4)));
            }
#pragma unroll
            for (int m = 0; m < 4; m++)
#pragma unroll
                for (int n = 0; n < 4; n++)
                    acc[m][n] = __builtin_amdgcn_mfma_f32_16x16x32_bf16(
                        af[m], bfr[n], acc[m][n], 0, 0, 0);
        }
        __builtin_amdgcn_s_setprio(0);
    }

    // epilogue (bias / rope / gelu / split-with-compaction / bf16)
    const int which = (n0 + wn * 64) >> 9;      // constant per wave
#pragma unroll
    for (int m = 0; m < 4; m++)
#pragma unroll
        for (int rr = 0; rr < 4; rr++) {
            int row = m0 + wm * 64 + m * 16 + l4 * 4 + rr;
            int orow = row;
            if ((flags & FLAG_SPLIT) && which > 0) orow = invidx[row];  // K/V: compact slot
#pragma unroll
            for (int n = 0; n < 4; n++) {
                int colg = n0 + wn * 64 + n * 16 + l15;
                float cv = acc[m][n][rr];
                if (bias) cv += bias[colg];
                // fused RoPE for q/k sections (original row's tables, pre-scatter)
                if ((flags & FLAG_ROPE) && which < 2 && n < 2) {
                    float partner = __shfl_xor(cv, 1, 64);
                    int i = (n * 16 + l15) >> 1;
                    float cc = ct[row * 16 + i], ss = st[row * 16 + i];
                    cv = (l15 & 1) ? (cv * cc + partner * ss) : (cv * cc - partner * ss);
                }
                if (flags & FLAG_GELU) cv = 0.5f * cv * (1.0f + erff(cv * 0.70710678118f));
                if (flags & FLAG_SPLIT) {
                    if (orow >= 0) {
                        u16* dst = which == 0 ? (u16*)Cq : which == 1 ? (u16*)Ck : (u16*)Cv;
                        dst[(size_t)orow * 512 + (colg & 511)] = f2bf(cv);
                    }
                } else {
                    ((u16*)Cq)[(size_t)row * N + colg] = f2bf(cv);
                }
            }
        }
}

// ---------------- per-head transpose of compacted V: vc (nk, NH*HD) -> vTc (NH, HD, SEQ) ----------------
__global__ void transpose_c(const u16* __restrict__ vc, const int* __restrict__ nkp,
                            u16* __restrict__ vTc) {
    int nk = *nkp;
    int s0 = blockIdx.x * 64;
    if (s0 >= ((nk + 63) & ~63)) return;        // past last compacted tile
    __shared__ __align__(16) u16 tile[64][80];
    int h = blockIdx.y;
    int t = threadIdx.x;               // 256
#pragma unroll
    for (int p = 0; p < 2; p++) {
        int c = p * 256 + t;
        int r = c >> 3, j = c & 7;
        u16x8 vv = {};
        if (s0 + r < nk)
            vv = *(const u16x8*)(vc + (size_t)(s0 + r) * DIM + h * HDIM + j * 8);
        *(u16x8*)&tile[r][j * 8] = vv;
    }
    __syncthreads();
#pragma unroll
    for (int p = 0; p < 2; p++) {
        int c = p * 256 + t;
        int d = c >> 3, j = c & 7;
        u16x8 vv;
#pragma unroll
        for (int i = 0; i < 8; i++) vv[i] = tile[j * 8 + i][d];
        *(u16x8*)(vTc + ((size_t)h * HDIM + d) * SEQ + s0 + j * 8) = vv;
    }
}

// ---------------- flash attention over COMPACTED keys: 32 q/wave, KV-split x3, LDS-P ----------------
// No softmax shift: P = exp2(sacc) directly for all tiles except the last
// (which applies the -inf pad mask). Row-sum via ones-MFMA.
__global__ __launch_bounds__(256, 3) void fattn_kernel(
    const u16* __restrict__ q, const u16* __restrict__ k,
    const u16* __restrict__ vT, const float* __restrict__ maskc,
    const int* __restrict__ nkp,
    u16* __restrict__ Opart, float* __restrict__ lpart)
{
    __shared__ __align__(16) u16 k_s[2][64 * 64];     // 16 KB [buf][key][d] swizzled image
    __shared__ __align__(16) u16 vt_s[2][64 * 64];    // 16 KB [buf][d][key] swizzled image
    __shared__ __align__(16) u16 p_s[4][32 * 64];     // 16 KB per-wave [q][key] swizzled

    const int t = threadIdx.x;
    const int lane = t & 63;
    const int w = t >> 6;
    const int h = blockIdx.x;
    const int q0 = blockIdx.y * 128;
    const int split = blockIdx.z;
    const int nk = *nkp;
    const int ntiles = (nk + 63) >> 6;
    const int tstart = (split * ntiles) / 3;
    const int tend   = ((split + 1) * ntiles) / 3;
    const int l15 = lane & 15, g = lane >> 4;

    // Q as B-frags, straight from global: q-row = q0+w*32+qh*16+l15, d = g*8+j (+32)
    bf16x8 qf[2][2];
#pragma unroll
    for (int qh = 0; qh < 2; qh++) {
        const u16* qrow = q + (size_t)(q0 + w * 32 + qh * 16 + l15) * DIM + h * HDIM;
        qf[qh][0] = *(const bf16x8*)(qrow + g * 8);
        qf[qh][1] = *(const bf16x8*)(qrow + g * 8 + 32);
    }

    // ones A-fragment (bf16 1.0 = 0x3F80) for the row-sum MFMA
    const bf16x8 ones = (bf16x8){16256, 16256, 16256, 16256, 16256, 16256, 16256, 16256};

    f32x4 O[2][4];                    // O^T: [qh][dt], reg r -> d = dt*16+4g+r, col q
    f32x4 lacc[2];                    // row-sum accumulator (all regs equal)
#pragma unroll
    for (int qh = 0; qh < 2; qh++) {
#pragma unroll
        for (int dt = 0; dt < 4; dt++) O[qh][dt] = (f32x4){0.f, 0.f, 0.f, 0.f};
        lacc[qh] = (f32x4){0.f, 0.f, 0.f, 0.f};
    }

    char* pbase = (char*)p_s[w];
    const int psw = (l15 & 7) << 4;

    auto stage = [&](int buf, int kb2) {
#pragma unroll
        for (int i = 0; i < 2; i++) {
            int c = (w * 2 + i) * 64 + lane;
            int r = c >> 3, j = (c & 7) ^ (r & 7);
            gload_lds16(k + (size_t)(kb2 + r) * DIM + h * HDIM + j * 8,
                        (char*)k_s + buf * 8192 + (w * 2 + i) * 1024);
            gload_lds16(vT + ((size_t)h * HDIM + r) * SEQ + kb2 + j * 8,
                        (char*)vt_s + buf * 8192 + (w * 2 + i) * 1024);
        }
    };

    if (tstart < tend) stage(0, tstart * 64);
    for (int ti = tstart; ti < tend; ti++) {
        const int cur = (ti - tstart) & 1;
        const int kb = ti * 64;
        asm volatile("s_waitcnt vmcnt(0)" ::: "memory");
        __syncthreads();
        if (ti + 1 < tend) stage(cur ^ 1, kb + 64);

        char* kcur = (char*)k_s + cur * 8192;
        char* vcur = (char*)vt_s + cur * 8192;

        // ---- QK^T (swapped): 2 independent chains (qh) off shared K A-frags ----
        f32x4 sacc[2][4];
        __builtin_amdgcn_s_setprio(1);
#pragma unroll
        for (int kt = 0; kt < 4; kt++) {
            int key = kt * 16 + l15;
            int ksw = (key & 7) << 4;
            char* kbase = kcur + key * 128;
            bf16x8 a0 = *(bf16x8*)(kbase + ((g * 16)      ^ ksw));
            bf16x8 a1 = *(bf16x8*)(kbase + ((g * 16 + 64) ^ ksw));
#pragma unroll
            for (int qh = 0; qh < 2; qh++) {
                f32x4 z = (f32x4){0.f, 0.f, 0.f, 0.f};
                z = __builtin_amdgcn_mfma_f32_16x16x32_bf16(a0, qf[qh][0], z, 0, 0, 0);
                z = __builtin_amdgcn_mfma_f32_16x16x32_bf16(a1, qf[qh][1], z, 0, 0, 0);
                sacc[qh][kt] = z;
            }
        }
        __builtin_amdgcn_s_setprio(0);

        // ---- P = exp2(sacc) [+pad mask only on the LAST tile] + b64 pack ----
        const bool haspad = (ti == ntiles - 1);
        if (!haspad) {
#pragma unroll
            for (int qh = 0; qh < 2; qh++)
#pragma unroll
                for (int kt = 0; kt < 4; kt++) {
                    float p0 = exp2f_fast(sacc[qh][kt][0]);
                    float p1 = exp2f_fast(sacc[qh][kt][1]);
                    float p2 = exp2f_fast(sacc[qh][kt][2]);
                    float p3 = exp2f_fast(sacc[qh][kt][3]);
                    uint2 pk;
                    pk.x = cvtpk(p0, p1);
                    pk.y = cvtpk(p2, p3);
                    int colb = (kt * 16 + g * 4) * 2;      // byte col, 8B aligned
                    *(uint2*)(pbase + (qh * 16 + l15) * 128 + (colb ^ psw)) = pk;
                }
        } else {
            float4 mf4[4];
#pragma unroll
            for (int kt = 0; kt < 4; kt++)
                mf4[kt] = *(const float4*)(maskc + kb + kt * 16 + g * 4);
#pragma unroll
            for (int qh = 0; qh < 2; qh++)
#pragma unroll
                for (int kt = 0; kt < 4; kt++) {
                    float p0 = exp2f_fast(sacc[qh][kt][0] + mf4[kt].x);
                    float p1 = exp2f_fast(sacc[qh][kt][1] + mf4[kt].y);
                    float p2 = exp2f_fast(sacc[qh][kt][2] + mf4[kt].z);
                    float p3 = exp2f_fast(sacc[qh][kt][3] + mf4[kt].w);
                    uint2 pk;
                    pk.x = cvtpk(p0, p1);
                    pk.y = cvtpk(p2, p3);
                    int colb = (kt * 16 + g * 4) * 2;
                    *(uint2*)(pbase + (qh * 16 + l15) * 128 + (colb ^ psw)) = pk;
                }
        }

        // ---- PV: O^T += V^T(A) @ P(B); lacc += ones @ P (row sums) ----
        __builtin_amdgcn_s_setprio(1);
#pragma unroll
        for (int h2 = 0; h2 < 2; h2++) {
            bf16x8 pb[2];
#pragma unroll
            for (int qh = 0; qh < 2; qh++)
                pb[qh] = *(bf16x8*)(pbase + (qh * 16 + l15) * 128 +
                                    (((h2 * 4 + g) * 16) ^ psw));
#pragma unroll
            for (int dt = 0; dt < 4; dt++) {
                int d = dt * 16 + l15;
                bf16x8 va = *(bf16x8*)(vcur + d * 128 +
                                       (((h2 * 4 + g) * 16) ^ ((d & 7) << 4)));
#pragma unroll
                for (int qh = 0; qh < 2; qh++)
                    O[qh][dt] = __builtin_amdgcn_mfma_f32_16x16x32_bf16(
                        va, pb[qh], O[qh][dt], 0, 0, 0);
            }
#pragma unroll
            for (int qh = 0; qh < 2; qh++)
                lacc[qh] = __builtin_amdgcn_mfma_f32_16x16x32_bf16(
                    ones, pb[qh], lacc[qh], 0, 0, 0);
        }
        __builtin_amdgcn_s_setprio(0);
    }

    // ---- epilogue: unnormalized partial O (bf16) + partial row sums ----
#pragma unroll
    for (int qh = 0; qh < 2; qh++) {
        float lrun = lacc[qh][0];     // every lane holds the full sum for its q-col
        int row = q0 + w * 32 + qh * 16 + l15;
        u16* orow = Opart + (size_t)split * SEQ * DIM + (size_t)row * DIM + h * HDIM;
#pragma unroll
        for (int dt = 0; dt < 4; dt++)
#pragma unroll
            for (int r = 0; r < 4; r += 2) {
                unsigned int pk = cvtpk(O[qh][dt][r], O[qh][dt][r + 1]);
                *(unsigned int*)(orow + dt * 16 + 4 * g + r) = pk;
            }
        if (g == 0)
            lpart[((size_t)split * NH + h) * SEQ + row] = lrun;
    }
}

// ---------------- combine: out = (O0+O1+O2) / (l0+l1+l2), bf16, u16x8 vectorized ----------------
__global__ void attn_combine(const u16* __restrict__ Opart, const float* __restrict__ lpart,
                             u16* __restrict__ out) {
    int t = threadIdx.x;               // 256 threads = 4 rows x 64 col-groups
    int row = blockIdx.x * 4 + (t >> 6);
    int col = (t & 63) * 8;
    int h = col >> 6;
    float l = lpart[(size_t)h * SEQ + row]
            + lpart[((size_t)NH + h) * SEQ + row]
            + lpart[((size_t)2 * NH + h) * SEQ + row];
    float inv = 1.0f / l;
    const size_t SD = (size_t)SEQ * DIM;
    const u16* base = Opart + (size_t)row * DIM + col;
    u16x8 ua = *(const u16x8*)(base);
    u16x8 ub = *(const u16x8*)(base + SD);
    u16x8 uc = *(const u16x8*)(base + 2 * SD);
    u16x8 res;
#pragma unroll
    for (int j = 0; j < 8; j += 2) {
        float o0 = bf2f(ua[j])     + bf2f(ub[j])     + bf2f(uc[j]);
        float o1 = bf2f(ua[j + 1]) + bf2f(ub[j + 1]) + bf2f(uc[j + 1]);
        unsigned int pk = cvtpk(o0 * inv, o1 * inv);
        res[j]     = (u16)(pk & 0xffff);
        res[j + 1] = (u16)(pk >> 16);
    }
    *(u16x8*)(out + (size_t)row * DIM + col) = res;
}

extern "C" void kernel_launch(void* const* d_in, const int* in_sizes, int n_in,
                              void* d_out, int out_size, void* d_ws, size_t ws_size,
                              hipStream_t stream) {
    const float* x      = (const float*)d_in[0];
    const float* gammas = (const float*)d_in[1];
    const float* betas  = (const float*)d_in[2];
    const float* wq     = (const float*)d_in[3];
    const float* wk     = (const float*)d_in[4];
    const float* wv     = (const float*)d_in[5];
    const float* wo     = (const float*)d_in[6];
    const float* bo     = (const float*)d_in[7];
    const float* w1     = (const float*)d_in[8];
    const float* b1     = (const float*)d_in[9];
    const float* w2     = (const float*)d_in[10];
    const float* b2     = (const float*)d_in[11];
    const int*   mask   = (const int*)d_in[12];
    float* out = (float*)d_out;

    // ---- workspace layout (bytes); peak ~40.5 MB ----
    char* wsb = (char*)d_ws;
    u16*   h1b   = (u16*)(wsb + 0);                 // 4 MB; LN1 out; then attnb/f1b
    u16*   kc    = (u16*)(wsb + (4ull  << 20));     // 4 MB compacted K (qkv epilogue scatter)
    u16*   vc    = (u16*)(wsb + (8ull  << 20));     // 4 MB compacted V
    u16*   vTc   = (u16*)(wsb + (12ull << 20));     // 4 MB compacted V^T
    u16*   qb    = (u16*)(wsb + (16ull << 20));     // 4 MB; reused as h2b
    u16*   Opart = (u16*)(wsb + (20ull << 20));     // 12 MB: 3 splits x 4 MB (20-32)
    u16*   x2b   = (u16*)(wsb + (20ull << 20));     // 4 MB bf16 x2 (over dead Opart)
    u16*   wqkvT = (u16*)(wsb + (32ull << 20));     // 1.5 MB
    u16*   woT   = wqkvT + 1536 * 512;              // 0.5 MB
    u16*   w1T   = woT   + 512 * 512;               // 2 MB
    u16*   w2T   = w1T   + 2048 * 512;              // 2 MB (ends 38 MB)
    float* maskc = (float*)(wsb + (38ull << 20));   // 16 KB
    int*   invidx= (int*)(wsb + (38ull << 20) + (64 << 10));   // 16 KB
    int*   nkp   = (int*)(wsb + (38ull << 20) + (128 << 10));  // 4 B
    float* ct    = (float*)(wsb + (39ull << 20));   // 256 KB
    float* st    = ct + 65536;                      // 256 KB
    float* lpart = (float*)(wsb + (40ull << 20));   // 384 KB
    u16*   f1b   = h1b;                             // 16 MB spanning slots 0-3 (FFN phase)
    u16*   h2b   = qb;
    u16*   attnb = h1b;

    // 0. fused prep: LN1 + mask scan (invidx) + rope tables + weight converts
    prep_kernel<<<SEQ / 4 + 1 + 256 + 3072, 256, 0, stream>>>(
        x, h1b, gammas, betas, wq, wk, wv, wo, w1, w2,
        wqkvT, woT, w1T, w2T, mask, maskc, invidx, nkp, ct, st);
    // 1. fused QKV projection + RoPE; K/V scattered directly to compacted slots
    gemm128<<<dim3(1536 / 128, SEQ / 128), 256, 0, stream>>>(
        h1b, wqkvT, nullptr, qb, kc, vc, ct, st, invidx,
        SEQ, 1536, DIM, FLAG_SPLIT | FLAG_BF16 | FLAG_ROPE);
    // 2. per-head transpose of compacted V (early-exit past last tile)
    transpose_c<<<dim3(SEQ / 64, NH), 256, 0, stream>>>(vc, nkp, vTc);
    // 3. attention over compacted keys, KV-split x3 (partials), then combine
    fattn_kernel<<<dim3(NH, SEQ / 128, KSPLIT), 256, 0, stream>>>(
        qb, kc, vTc, maskc, nkp, Opart, lpart);
    attn_combine<<<SEQ / 4, 256, 0, stream>>>(Opart, lpart, attnb);
    // 4. x2 = bf16(x + attn@wo + bo)  [x2b over dead Opart], BK=128
    gemm_bf16<1><<<dim3(DIM / 64, SEQ / 64), 256, 0, stream>>>(
        attnb, woT, bo, (const void*)x, x2b, SEQ, DIM, DIM, FLAG_BF16);
    // 5. h2 = LN(x2b) (bf16 in/out, wave-per-row)
    ln_bf16_kernel<<<SEQ / 4, 256, 0, stream>>>(x2b, h2b, gammas, betas, 1);
    // 6. f1 = gelu(h2@w1 + b1) (bf16), 128x128 tiles
    gemm128<<<dim3(FFD / 128, SEQ / 128), 256, 0, stream>>>(
        h2b, w1T, b1, f1b, nullptr, nullptr, nullptr, nullptr, nullptr,
        SEQ, FFD, DIM, FLAG_BF16 | FLAG_GELU);
    // 7. out = x2b + f1@w2 + b2 (f32 out, bf16 resid), BK=128
    gemm_bf16<1><<<dim3(DIM / 64, SEQ / 64), 256, 0, stream>>>(
        f1b, w2T, b2, (const void*)x2b, out, SEQ, DIM, FFD, FLAG_RESID_BF16);
}

// Round 21
// 140.528 us; speedup vs baseline: 1.9049x; 1.0618x over previous
//
#include <hip/hip_runtime.h>
#include <math.h>

constexpr int SEQ  = 4096;
constexpr int DIM  = 512;
constexpr int NH   = 8;
constexpr int HDIM = 64;
constexpr int FFD  = 2048;
constexpr int KSPLIT = 3;

typedef unsigned short u16;
typedef __attribute__((ext_vector_type(8))) short bf16x8;
typedef __attribute__((ext_vector_type(4))) float f32x4;
typedef __attribute__((ext_vector_type(8))) unsigned short u16x8;

// score scale: (1/8) * log2(e), folded into wq. Softmax computed in exp2 domain.
// NO static shift: in compact key space all valid keys share mask=const, which
// cancels in the normalization; |s| <= ~1.2 so exp2 is overflow-safe. Only the
// tail-pad entries of the LAST tile carry -inf (exp2 -> exact 0).
#define LOG2E      1.4426950408889634f
#define QSCALE     (0.125f * LOG2E)
#define MASK_OFF   (-1.4427e9f)

static __device__ __forceinline__ u16 f2bf(float x) {
    union { float f; unsigned int u; } v; v.f = x;
    unsigned int r = v.u + 0x7fff + ((v.u >> 16) & 1);
    return (u16)(r >> 16);
}
static __device__ __forceinline__ float bf2f(u16 h) {
    union { unsigned int u; float f; } v; v.u = ((unsigned int)h) << 16;
    return v.f;
}
static __device__ __forceinline__ unsigned int cvtpk(float lo, float hi) {
    unsigned int r;
    asm volatile("v_cvt_pk_bf16_f32 %0, %1, %2" : "=v"(r) : "v"(lo), "v"(hi));
    return r;
}
static __device__ __forceinline__ float exp2f_fast(float x) {
    float r; asm volatile("v_exp_f32 %0, %1" : "=v"(r) : "v"(x)); return r;
}
static __device__ __forceinline__ void gload_lds16(const void* g, void* l) {
    __builtin_amdgcn_global_load_lds(
        (const __attribute__((address_space(1))) unsigned int*)g,
        (__attribute__((address_space(3))) unsigned int*)l, 16, 0, 0);
}

// ---------------- fused prep: LN1 (wave/row) + mask scan + rope tables + weight converts ----------------
__global__ void prep_kernel(const float* __restrict__ x, u16* __restrict__ h1,
                            const float* __restrict__ gammas, const float* __restrict__ betas,
                            const float* __restrict__ wq, const float* __restrict__ wk,
                            const float* __restrict__ wv, const float* __restrict__ wo,
                            const float* __restrict__ w1, const float* __restrict__ w2,
                            u16* __restrict__ wqkvT, u16* __restrict__ woT,
                            u16* __restrict__ w1T, u16* __restrict__ w2T,
                            const int* __restrict__ mask, float* __restrict__ maskc,
                            int* __restrict__ invidx, int* __restrict__ nkp,
                            float* __restrict__ ct, float* __restrict__ st) {
    __shared__ float smem[1056];
    int b = blockIdx.x;
    int t = threadIdx.x;
    if (b < SEQ / 4) {                          // LN1: 4 rows/block, one wave each, no LDS
        int wv_ = t >> 6, lane = t & 63;
        int row = b * 4 + wv_;
        const float* xr = x + (size_t)row * DIM + lane * 8;
        float4 a0 = *(const float4*)xr;
        float4 a1 = *(const float4*)(xr + 4);
        float f[8] = {a0.x, a0.y, a0.z, a0.w, a1.x, a1.y, a1.z, a1.w};
        float s = 0.f, qs = 0.f;
#pragma unroll
        for (int i = 0; i < 8; i++) { s += f[i]; qs += f[i] * f[i]; }
#pragma unroll
        for (int o = 1; o < 64; o <<= 1) {
            s  += __shfl_xor(s, o, 64);
            qs += __shfl_xor(qs, o, 64);
        }
        float mean = s / DIM;
        float var  = qs / DIM - mean * mean;
        float rstd = rsqrtf(var + 1e-5f);
        float g = gammas[0], be = betas[0];
        u16x8 res;
#pragma unroll
        for (int i = 0; i < 8; i += 2) {
            unsigned int pk = cvtpk(g * ((f[i] - mean) * rstd) + be,
                                    g * ((f[i + 1] - mean) * rstd) + be);
            res[i]     = (u16)(pk & 0xffff);
            res[i + 1] = (u16)(pk >> 16);
        }
        *(u16x8*)(h1 + (size_t)row * DIM + lane * 8) = res;
        return;
    }
    b -= SEQ / 4;
    if (b < 1) {                                // mask-compaction scan (1 block, 256 thr x 16)
        __shared__ int cnt[256];
        int base = t * 16;
        int loc[16]; int c = 0;
#pragma unroll
        for (int i = 0; i < 16; i++) { loc[i] = mask[base + i]; c += (loc[i] != 0); }
        cnt[t] = c;
        __syncthreads();
        for (int o = 1; o < 256; o <<= 1) {
            int v = (t >= o) ? cnt[t - o] : 0;
            __syncthreads();
            cnt[t] += v;
            __syncthreads();
        }
        int pos = cnt[t] - c;                   // exclusive prefix
        int total = cnt[255];
#pragma unroll
        for (int i = 0; i < 16; i++)
            invidx[base + i] = loc[i] ? pos++ : -1;
#pragma unroll
        for (int i = 0; i < 16; i++)
            maskc[base + i] = (base + i < total) ? 0.0f : MASK_OFF;
        if (t == 0) *nkp = total;
        return;
    }
    b -= 1;
    if (b < 256) {                              // rope cos/sin tables: [s][i], i<16
        int idx = b * 256 + t;                  // 65536 = 4096*16
        int s = idx >> 4, i = idx & 15;
        float invf = expf(-(float)i * (9.2103403719761836f / 16.0f));  // 10000^(-i/16)
        float freq = (float)s * invf;
        ct[idx] = cosf(freq);
        st[idx] = sinf(freq);
        return;
    }
    b -= 256;
    const float* src; u16* dst; int K, N; float scale = 1.f;
    if (b < 256)       { src = wq; dst = wqkvT;            K = 512;  N = 512; scale = QSCALE; }
    else if (b < 512)  { src = wk; dst = wqkvT + 512*512;  K = 512;  N = 512; b -= 256; }
    else if (b < 768)  { src = wv; dst = wqkvT + 1024*512; K = 512;  N = 512; b -= 512; }
    else if (b < 1024) { src = wo; dst = woT;              K = 512;  N = 512; b -= 768; }
    else if (b < 2048) { src = w1; dst = w1T;              K = 512;  N = 2048; b -= 1024; }
    else               { src = w2; dst = w2T;              K = 2048; N = 512;  b -= 2048; }
    float (*tile)[33] = (float(*)[33])smem;
    int tiles_x = N / 32;
    int n0 = (b % tiles_x) * 32, k0 = (b / tiles_x) * 32;
    int tx = t & 31, ty = t >> 5;               // 32 x 8
#pragma unroll
    for (int i = 0; i < 4; i++) {
        int kk = ty + i * 8;
        tile[kk][tx] = src[(size_t)(k0 + kk) * N + n0 + tx];
    }
    __syncthreads();
#pragma unroll
    for (int i = 0; i < 4; i++) {
        int nn = ty + i * 8;
        dst[(size_t)(n0 + nn) * K + k0 + tx] = f2bf(scale * tile[tx][nn]);
    }
}

// ---------------- LayerNorm LN2, bf16 in/out, wave-per-row ----------------
__global__ void ln_bf16_kernel(const u16* __restrict__ x, u16* __restrict__ out,
                               const float* __restrict__ gammas, const float* __restrict__ betas,
                               int gi) {
    int t = threadIdx.x;
    int wv_ = t >> 6, lane = t & 63;
    int row = blockIdx.x * 4 + wv_;
    u16x8 v = *(const u16x8*)(x + (size_t)row * DIM + lane * 8);
    float f[8];
    float s = 0.f, qs = 0.f;
#pragma unroll
    for (int i = 0; i < 8; i++) { f[i] = bf2f(v[i]); s += f[i]; qs += f[i] * f[i]; }
#pragma unroll
    for (int o = 1; o < 64; o <<= 1) {
        s  += __shfl_xor(s, o, 64);
        qs += __shfl_xor(qs, o, 64);
    }
    float mean = s / DIM;
    float var  = qs / DIM - mean * mean;
    float rstd = rsqrtf(var + 1e-5f);
    float g = gammas[gi], be = betas[gi];
    u16x8 res;
#pragma unroll
    for (int i = 0; i < 8; i += 2) {
        unsigned int pk = cvtpk(g * ((f[i] - mean) * rstd) + be,
                                g * ((f[i + 1] - mean) * rstd) + be);
        res[i]     = (u16)(pk & 0xffff);
        res[i + 1] = (u16)(pk >> 16);
    }
    *(u16x8*)(out + (size_t)row * DIM + lane * 8) = res;
}

constexpr int FLAG_BF16 = 1, FLAG_GELU = 2, FLAG_SPLIT = 4, FLAG_ROPE = 8, FLAG_RESID_BF16 = 16;

// ---------------- bf16 MFMA GEMM, 64-wide tiles, BK=128 (wo / w2): C = A @ WT^T ----------------
template<int MF>
__global__ __launch_bounds__(256) void gemm_bf16(
    const u16* __restrict__ A, const u16* __restrict__ WT,
    const float* __restrict__ bias, const void* __restrict__ resid,
    void* __restrict__ Cq, int M, int N, int K, int flags)
{
    constexpr int BM = MF * 64;
    __shared__ __align__(16) u16 At[2][BM * 128];
    __shared__ __align__(16) u16 Bt[2][64 * 128];
    const int t = threadIdx.x, lane = t & 63, w = t >> 6;
    const int n0 = blockIdx.x * 64, m0 = blockIdx.y * BM;
    const int l15 = lane & 15, l4 = lane >> 4;

    f32x4 acc[MF][4];
#pragma unroll
    for (int m = 0; m < MF; m++)
#pragma unroll
        for (int n = 0; n < 4; n++) acc[m][n] = (f32x4){0.f, 0.f, 0.f, 0.f};

    auto stage = [&](int buf, int k0) {
#pragma unroll
        for (int i = 0; i < MF * 4; i++) {       // A: BM rows x 16 chunks
            int c = (w * MF * 4 + i) * 64 + lane;
            int r = c >> 4, jj = (c & 15) ^ (r & 7);
            gload_lds16(A + (size_t)(m0 + r) * K + k0 + jj * 8,
                        (char*)At[buf] + (w * MF * 4 + i) * 1024);
        }
#pragma unroll
        for (int i = 0; i < 4; i++) {            // B: 64 rows x 16 chunks
            int c = (w * 4 + i) * 64 + lane;
            int r = c >> 4, jj = (c & 15) ^ (r & 7);
            gload_lds16(WT + (size_t)(n0 + r) * K + k0 + jj * 8,
                        (char*)Bt[buf] + (w * 4 + i) * 1024);
        }
    };

    const int NT = K / 128;
    stage(0, 0);
    for (int ti = 0; ti < NT; ti++) {
        const int cur = ti & 1;
        asm volatile("s_waitcnt vmcnt(0)" ::: "memory");
        __syncthreads();
        if (ti + 1 < NT) stage(cur ^ 1, (ti + 1) * 128);
        __builtin_amdgcn_s_setprio(1);
#pragma unroll
        for (int kk = 0; kk < 4; kk++) {
            bf16x8 af[MF], bfr[4];
#pragma unroll
            for (int m = 0; m < MF; m++) {
                int row = w * MF * 16 + m * 16 + l15;
                af[m] = *(bf16x8*)((char*)At[cur] + row * 256 +
                                   ((kk * 64 + l4 * 16) ^ ((row & 7) << 4)));
            }
#pragma unroll
            for (int n = 0; n < 4; n++) {
                int row = n * 16 + l15;
                bfr[n] = *(bf16x8*)((char*)Bt[cur] + row * 256 +
                                    ((kk * 64 + l4 * 16) ^ ((row & 7) << 4)));
            }
#pragma unroll
            for (int m = 0; m < MF; m++)
#pragma unroll
                for (int n = 0; n < 4; n++)
                    acc[m][n] = __builtin_amdgcn_mfma_f32_16x16x32_bf16(
                        af[m], bfr[n], acc[m][n], 0, 0, 0);
        }
        __builtin_amdgcn_s_setprio(0);
    }

#pragma unroll
    for (int m = 0; m < MF; m++)
#pragma unroll
        for (int rr = 0; rr < 4; rr++) {
            int row = m0 + w * MF * 16 + m * 16 + l4 * 4 + rr;
#pragma unroll
            for (int n = 0; n < 4; n++) {
                int colg = n0 + n * 16 + l15;
                float cv = acc[m][n][rr];
                if (bias) cv += bias[colg];
                if (flags & FLAG_GELU) cv = 0.5f * cv * (1.0f + erff(cv * 0.70710678118f));
                if (resid) {
                    if (flags & FLAG_RESID_BF16)
                        cv += bf2f(((const u16*)resid)[(size_t)row * N + colg]);
                    else
                        cv += ((const float*)resid)[(size_t)row * N + colg];
                }
                if (flags & FLAG_BF16) {
                    ((u16*)Cq)[(size_t)row * N + colg] = f2bf(cv);
                } else {
                    ((float*)Cq)[(size_t)row * N + colg] = cv;
                }
            }
        }
}

// ---------------- bf16 MFMA GEMM, 64x128 tile (qkv): 3 blocks/CU exact, balanced ----------------
// BM=64, BN=128, BK=64; 4 waves 2x2 (32 rows x 64 cols each). LDS 48 KB.
// Grid (N/128, M/64) = (12, 64) = 768 blocks = 3/CU exact (vs gemm128's 384@2/CU imbalance).
__global__ __launch_bounds__(256, 3) void gemm_qkv(
    const u16* __restrict__ A, const u16* __restrict__ WT,
    void* __restrict__ Cq, void* __restrict__ Ck, void* __restrict__ Cv,
    const float* __restrict__ ct, const float* __restrict__ st,
    const int* __restrict__ invidx,
    int M, int N, int K)
{
    __shared__ __align__(16) u16 At[2][64 * 64];    //  8 KB per buf
    __shared__ __align__(16) u16 Bt[2][128 * 64];   // 16 KB per buf
    const int t = threadIdx.x, lane = t & 63, w = t >> 6;
    const int wm = w >> 1, wn = w & 1;
    const int n0 = blockIdx.x * 128, m0 = blockIdx.y * 64;
    const int l15 = lane & 15, l4 = lane >> 4;

    f32x4 acc[2][4];
#pragma unroll
    for (int m = 0; m < 2; m++)
#pragma unroll
        for (int n = 0; n < 4; n++) acc[m][n] = (f32x4){0.f, 0.f, 0.f, 0.f};

    auto stage = [&](int buf, int k0) {
#pragma unroll
        for (int i = 0; i < 2; i++) {            // A: 64 rows x 8 chunks = 512
            int c = (w * 2 + i) * 64 + lane;
            int r = c >> 3, j = (c & 7) ^ (r & 7);
            gload_lds16(A + (size_t)(m0 + r) * K + k0 + j * 8,
                        (char*)At[buf] + (w * 2 + i) * 1024);
        }
#pragma unroll
        for (int i = 0; i < 4; i++) {            // B: 128 rows x 8 chunks = 1024
            int c = (w * 4 + i) * 64 + lane;
            int r = c >> 3, j = (c & 7) ^ (r & 7);
            gload_lds16(WT + (size_t)(n0 + r) * K + k0 + j * 8,
                        (char*)Bt[buf] + (w * 4 + i) * 1024);
        }
    };

    const int NT = K / 64;
    stage(0, 0);
    for (int ti = 0; ti < NT; ti++) {
        const int cur = ti & 1;
        asm volatile("s_waitcnt vmcnt(0)" ::: "memory");
        __syncthreads();
        if (ti + 1 < NT) stage(cur ^ 1, (ti + 1) * 64);
        __builtin_amdgcn_s_setprio(1);
#pragma unroll
        for (int kk = 0; kk < 2; kk++) {
            bf16x8 af[2], bfr[4];
#pragma unroll
            for (int m = 0; m < 2; m++) {
                int row = wm * 32 + m * 16 + l15;
                af[m] = *(bf16x8*)((char*)At[cur] + row * 128 +
                                   ((kk * 64 + l4 * 16) ^ ((row & 7) << 4)));
            }
#pragma unroll
            for (int n = 0; n < 4; n++) {
                int row = wn * 64 + n * 16 + l15;
                bfr[n] = *(bf16x8*)((char*)Bt[cur] + row * 128 +
                                    ((kk * 64 + l4 * 16) ^ ((row & 7) << 4)));
            }
#pragma unroll
            for (int m = 0; m < 2; m++)
#pragma unroll
                for (int n = 0; n < 4; n++)
                    acc[m][n] = __builtin_amdgcn_mfma_f32_16x16x32_bf16(
                        af[m], bfr[n], acc[m][n], 0, 0, 0);
        }
        __builtin_amdgcn_s_setprio(0);
    }

    // epilogue: rope on q/k head-cols < 32, split-scatter K/V to compacted slots
    const int which = (n0 + wn * 64) >> 9;      // constant per wave (128 | 512)
#pragma unroll
    for (int m = 0; m < 2; m++)
#pragma unroll
        for (int rr = 0; rr < 4; rr++) {
            int row = m0 + wm * 32 + m * 16 + l4 * 4 + rr;
            int orow = (which > 0) ? invidx[row] : row;
#pragma unroll
            for (int n = 0; n < 4; n++) {
                int colg = n0 + wn * 64 + n * 16 + l15;
                float cv = acc[m][n][rr];
                if (which < 2 && n < 2) {        // RoPE (head-col = n*16+l15 < 32)
                    float partner = __shfl_xor(cv, 1, 64);
                    int i = (n * 16 + l15) >> 1;
                    float cc = ct[row * 16 + i], ss = st[row * 16 + i];
                    cv = (l15 & 1) ? (cv * cc + partner * ss) : (cv * cc - partner * ss);
                }
                if (orow >= 0) {
                    u16* dst = which == 0 ? (u16*)Cq : which == 1 ? (u16*)Ck : (u16*)Cv;
                    dst[(size_t)orow * 512 + (colg & 511)] = f2bf(cv);
                }
            }
        }
}

// ---------------- bf16 MFMA GEMM, 128x128 tile (ffn1) ----------------
__global__ __launch_bounds__(256) void gemm128(
    const u16* __restrict__ A, const u16* __restrict__ WT,
    const float* __restrict__ bias,
    void* __restrict__ Cq,
    int M, int N, int K, int flags)
{
    __shared__ __align__(16) u16 At[2][128 * 64];   // 16 KB per buf, swizzled image
    __shared__ __align__(16) u16 Bt[2][128 * 64];
    const int t = threadIdx.x, lane = t & 63, w = t >> 6;
    const int wm = w >> 1, wn = w & 1;
    const int n0 = blockIdx.x * 128, m0 = blockIdx.y * 128;
    const int l15 = lane & 15, l4 = lane >> 4;

    f32x4 acc[4][4];
#pragma unroll
    for (int m = 0; m < 4; m++)
#pragma unroll
        for (int n = 0; n < 4; n++) acc[m][n] = (f32x4){0.f, 0.f, 0.f, 0.f};

    auto stage = [&](int buf, int k0) {
#pragma unroll
        for (int i = 0; i < 4; i++) {
            int c = (w * 4 + i) * 64 + lane;
            int r = c >> 3, j = (c & 7) ^ (r & 7);
            gload_lds16(A + (size_t)(m0 + r) * K + k0 + j * 8,
                        (char*)At[buf] + (w * 4 + i) * 1024);
            gload_lds16(WT + (size_t)(n0 + r) * K + k0 + j * 8,
                        (char*)Bt[buf] + (w * 4 + i) * 1024);
        }
    };

    const int NT = K / 64;
    stage(0, 0);
    for (int ti = 0; ti < NT; ti++) {
        const int cur = ti & 1;
        asm volatile("s_waitcnt vmcnt(0)" ::: "memory");
        __syncthreads();
        if (ti + 1 < NT) stage(cur ^ 1, (ti + 1) * 64);
        __builtin_amdgcn_s_setprio(1);
#pragma unroll
        for (int kk = 0; kk < 2; kk++) {
            bf16x8 af[4], bfr[4];
#pragma unroll
            for (int m = 0; m < 4; m++) {
                int row = wm * 64 + m * 16 + l15;
                af[m] = *(bf16x8*)((char*)At[cur] + row * 128 +
                                   ((kk * 64 + l4 * 16) ^ ((row & 7) << 4)));
            }
#pragma unroll
            for (int n = 0; n < 4; n++) {
                int row = wn * 64 + n * 16 + l15;
                bfr[n] = *(bf16x8*)((char*)Bt[cur] + row * 128 +
                                    ((kk * 64 + l4 * 16) ^ ((row & 7) << 4)));
            }
#pragma unroll
            for (int m = 0; m < 4; m++)
#pragma unroll
                for (int n = 0; n < 4; n++)
                    acc[m][n] = __builtin_amdgcn_mfma_f32_16x16x32_bf16(
                        af[m], bfr[n], acc[m][n], 0, 0, 0);
        }
        __builtin_amdgcn_s_setprio(0);
    }

    // epilogue (bias / gelu / bf16)
#pragma unroll
    for (int m = 0; m < 4; m++)
#pragma unroll
        for (int rr = 0; rr < 4; rr++) {
            int row = m0 + wm * 64 + m * 16 + l4 * 4 + rr;
#pragma unroll
            for (int n = 0; n < 4; n++) {
                int colg = n0 + wn * 64 + n * 16 + l15;
                float cv = acc[m][n][rr];
                if (bias) cv += bias[colg];
                if (flags & FLAG_GELU) cv = 0.5f * cv * (1.0f + erff(cv * 0.70710678118f));
                ((u16*)Cq)[(size_t)row * N + colg] = f2bf(cv);
            }
        }
}

// ---------------- per-head transpose of compacted V: vc (nk, NH*HD) -> vTc (NH, HD, SEQ) ----------------
__global__ void transpose_c(const u16* __restrict__ vc, const int* __restrict__ nkp,
                            u16* __restrict__ vTc) {
    int nk = *nkp;
    int s0 = blockIdx.x * 64;
    if (s0 >= ((nk + 63) & ~63)) return;        // past last compacted tile
    __shared__ __align__(16) u16 tile[64][80];
    int h = blockIdx.y;
    int t = threadIdx.x;               // 256
#pragma unroll
    for (int p = 0; p < 2; p++) {
        int c = p * 256 + t;
        int r = c >> 3, j = c & 7;
        u16x8 vv = {};
        if (s0 + r < nk)
            vv = *(const u16x8*)(vc + (size_t)(s0 + r) * DIM + h * HDIM + j * 8);
        *(u16x8*)&tile[r][j * 8] = vv;
    }
    __syncthreads();
#pragma unroll
    for (int p = 0; p < 2; p++) {
        int c = p * 256 + t;
        int d = c >> 3, j = c & 7;
        u16x8 vv;
#pragma unroll
        for (int i = 0; i < 8; i++) vv[i] = tile[j * 8 + i][d];
        *(u16x8*)(vTc + ((size_t)h * HDIM + d) * SEQ + s0 + j * 8) = vv;
    }
}

// ---------------- flash attention over COMPACTED keys: 32 q/wave, KV-split x3, LDS-P ----------------
// No softmax shift: P = exp2(sacc) directly for all tiles except the last
// (which applies the -inf pad mask). Row-sum via ones-MFMA.
__global__ __launch_bounds__(256, 3) void fattn_kernel(
    const u16* __restrict__ q, const u16* __restrict__ k,
    const u16* __restrict__ vT, const float* __restrict__ maskc,
    const int* __restrict__ nkp,
    u16* __restrict__ Opart, float* __restrict__ lpart)
{
    __shared__ __align__(16) u16 k_s[2][64 * 64];     // 16 KB [buf][key][d] swizzled image
    __shared__ __align__(16) u16 vt_s[2][64 * 64];    // 16 KB [buf][d][key] swizzled image
    __shared__ __align__(16) u16 p_s[4][32 * 64];     // 16 KB per-wave [q][key] swizzled

    const int t = threadIdx.x;
    const int lane = t & 63;
    const int w = t >> 6;
    const int h = blockIdx.x;
    const int q0 = blockIdx.y * 128;
    const int split = blockIdx.z;
    const int nk = *nkp;
    const int ntiles = (nk + 63) >> 6;
    const int tstart = (split * ntiles) / 3;
    const int tend   = ((split + 1) * ntiles) / 3;
    const int l15 = lane & 15, g = lane >> 4;

    // Q as B-frags, straight from global: q-row = q0+w*32+qh*16+l15, d = g*8+j (+32)
    bf16x8 qf[2][2];
#pragma unroll
    for (int qh = 0; qh < 2; qh++) {
        const u16* qrow = q + (size_t)(q0 + w * 32 + qh * 16 + l15) * DIM + h * HDIM;
        qf[qh][0] = *(const bf16x8*)(qrow + g * 8);
        qf[qh][1] = *(const bf16x8*)(qrow + g * 8 + 32);
    }

    // ones A-fragment (bf16 1.0 = 0x3F80) for the row-sum MFMA
    const bf16x8 ones = (bf16x8){16256, 16256, 16256, 16256, 16256, 16256, 16256, 16256};

    f32x4 O[2][4];                    // O^T: [qh][dt], reg r -> d = dt*16+4g+r, col q
    f32x4 lacc[2];                    // row-sum accumulator (all regs equal)
#pragma unroll
    for (int qh = 0; qh < 2; qh++) {
#pragma unroll
        for (int dt = 0; dt < 4; dt++) O[qh][dt] = (f32x4){0.f, 0.f, 0.f, 0.f};
        lacc[qh] = (f32x4){0.f, 0.f, 0.f, 0.f};
    }

    char* pbase = (char*)p_s[w];
    const int psw = (l15 & 7) << 4;

    auto stage = [&](int buf, int kb2) {
#pragma unroll
        for (int i = 0; i < 2; i++) {
            int c = (w * 2 + i) * 64 + lane;
            int r = c >> 3, j = (c & 7) ^ (r & 7);
            gload_lds16(k + (size_t)(kb2 + r) * DIM + h * HDIM + j * 8,
                        (char*)k_s + buf * 8192 + (w * 2 + i) * 1024);
            gload_lds16(vT + ((size_t)h * HDIM + r) * SEQ + kb2 + j * 8,
                        (char*)vt_s + buf * 8192 + (w * 2 + i) * 1024);
        }
    };

    if (tstart < tend) stage(0, tstart * 64);
    for (int ti = tstart; ti < tend; ti++) {
        const int cur = (ti - tstart) & 1;
        const int kb = ti * 64;
        asm volatile("s_waitcnt vmcnt(0)" ::: "memory");
        __syncthreads();
        if (ti + 1 < tend) stage(cur ^ 1, kb + 64);

        char* kcur = (char*)k_s + cur * 8192;
        char* vcur = (char*)vt_s + cur * 8192;

        // ---- QK^T (swapped): 2 independent chains (qh) off shared K A-frags ----
        f32x4 sacc[2][4];
        __builtin_amdgcn_s_setprio(1);
#pragma unroll
        for (int kt = 0; kt < 4; kt++) {
            int key = kt * 16 + l15;
            int ksw = (key & 7) << 4;
            char* kbase = kcur + key * 128;
            bf16x8 a0 = *(bf16x8*)(kbase + ((g * 16)      ^ ksw));
            bf16x8 a1 = *(bf16x8*)(kbase + ((g * 16 + 64) ^ ksw));
#pragma unroll
            for (int qh = 0; qh < 2; qh++) {
                f32x4 z = (f32x4){0.f, 0.f, 0.f, 0.f};
                z = __builtin_amdgcn_mfma_f32_16x16x32_bf16(a0, qf[qh][0], z, 0, 0, 0);
                z = __builtin_amdgcn_mfma_f32_16x16x32_bf16(a1, qf[qh][1], z, 0, 0, 0);
                sacc[qh][kt] = z;
            }
        }
        __builtin_amdgcn_s_setprio(0);

        // ---- P = exp2(sacc) [+pad mask only on the LAST tile] + b64 pack ----
        const bool haspad = (ti == ntiles - 1);
        if (!haspad) {
#pragma unroll
            for (int qh = 0; qh < 2; qh++)
#pragma unroll
                for (int kt = 0; kt < 4; kt++) {
                    float p0 = exp2f_fast(sacc[qh][kt][0]);
                    float p1 = exp2f_fast(sacc[qh][kt][1]);
                    float p2 = exp2f_fast(sacc[qh][kt][2]);
                    float p3 = exp2f_fast(sacc[qh][kt][3]);
                    uint2 pk;
                    pk.x = cvtpk(p0, p1);
                    pk.y = cvtpk(p2, p3);
                    int colb = (kt * 16 + g * 4) * 2;      // byte col, 8B aligned
                    *(uint2*)(pbase + (qh * 16 + l15) * 128 + (colb ^ psw)) = pk;
                }
        } else {
            float4 mf4[4];
#pragma unroll
            for (int kt = 0; kt < 4; kt++)
                mf4[kt] = *(const float4*)(maskc + kb + kt * 16 + g * 4);
#pragma unroll
            for (int qh = 0; qh < 2; qh++)
#pragma unroll
                for (int kt = 0; kt < 4; kt++) {
                    float p0 = exp2f_fast(sacc[qh][kt][0] + mf4[kt].x);
                    float p1 = exp2f_fast(sacc[qh][kt][1] + mf4[kt].y);
                    float p2 = exp2f_fast(sacc[qh][kt][2] + mf4[kt].z);
                    float p3 = exp2f_fast(sacc[qh][kt][3] + mf4[kt].w);
                    uint2 pk;
                    pk.x = cvtpk(p0, p1);
                    pk.y = cvtpk(p2, p3);
                    int colb = (kt * 16 + g * 4) * 2;
                    *(uint2*)(pbase + (qh * 16 + l15) * 128 + (colb ^ psw)) = pk;
                }
        }

        // ---- PV: O^T += V^T(A) @ P(B); lacc += ones @ P (row sums) ----
        __builtin_amdgcn_s_setprio(1);
#pragma unroll
        for (int h2 = 0; h2 < 2; h2++) {
            bf16x8 pb[2];
#pragma unroll
            for (int qh = 0; qh < 2; qh++)
                pb[qh] = *(bf16x8*)(pbase + (qh * 16 + l15) * 128 +
                                    (((h2 * 4 + g) * 16) ^ psw));
#pragma unroll
            for (int dt = 0; dt < 4; dt++) {
                int d = dt * 16 + l15;
                bf16x8 va = *(bf16x8*)(vcur + d * 128 +
                                       (((h2 * 4 + g) * 16) ^ ((d & 7) << 4)));
#pragma unroll
                for (int qh = 0; qh < 2; qh++)
                    O[qh][dt] = __builtin_amdgcn_mfma_f32_16x16x32_bf16(
                        va, pb[qh], O[qh][dt], 0, 0, 0);
            }
#pragma unroll
            for (int qh = 0; qh < 2; qh++)
                lacc[qh] = __builtin_amdgcn_mfma_f32_16x16x32_bf16(
                    ones, pb[qh], lacc[qh], 0, 0, 0);
        }
        __builtin_amdgcn_s_setprio(0);
    }

    // ---- epilogue: unnormalized partial O (bf16) + partial row sums ----
#pragma unroll
    for (int qh = 0; qh < 2; qh++) {
        float lrun = lacc[qh][0];     // every lane holds the full sum for its q-col
        int row = q0 + w * 32 + qh * 16 + l15;
        u16* orow = Opart + (size_t)split * SEQ * DIM + (size_t)row * DIM + h * HDIM;
#pragma unroll
        for (int dt = 0; dt < 4; dt++)
#pragma unroll
            for (int r = 0; r < 4; r += 2) {
                unsigned int pk = cvtpk(O[qh][dt][r], O[qh][dt][r + 1]);
                *(unsigned int*)(orow + dt * 16 + 4 * g + r) = pk;
            }
        if (g == 0)
            lpart[((size_t)split * NH + h) * SEQ + row] = lrun;
    }
}

// ---------------- combine: out = (O0+O1+O2) / (l0+l1+l2), bf16, u16x8 vectorized ----------------
__global__ void attn_combine(const u16* __restrict__ Opart, const float* __restrict__ lpart,
                             u16* __restrict__ out) {
    int t = threadIdx.x;               // 256 threads = 4 rows x 64 col-groups
    int row = blockIdx.x * 4 + (t >> 6);
    int col = (t & 63) * 8;
    int h = col >> 6;
    float l = lpart[(size_t)h * SEQ + row]
            + lpart[((size_t)NH + h) * SEQ + row]
            + lpart[((size_t)2 * NH + h) * SEQ + row];
    float inv = 1.0f / l;
    const size_t SD = (size_t)SEQ * DIM;
    const u16* base = Opart + (size_t)row * DIM + col;
    u16x8 ua = *(const u16x8*)(base);
    u16x8 ub = *(const u16x8*)(base + SD);
    u16x8 uc = *(const u16x8*)(base + 2 * SD);
    u16x8 res;
#pragma unroll
    for (int j = 0; j < 8; j += 2) {
        float o0 = bf2f(ua[j])     + bf2f(ub[j])     + bf2f(uc[j]);
        float o1 = bf2f(ua[j + 1]) + bf2f(ub[j + 1]) + bf2f(uc[j + 1]);
        unsigned int pk = cvtpk(o0 * inv, o1 * inv);
        res[j]     = (u16)(pk & 0xffff);
        res[j + 1] = (u16)(pk >> 16);
    }
    *(u16x8*)(out + (size_t)row * DIM + col) = res;
}

extern "C" void kernel_launch(void* const* d_in, const int* in_sizes, int n_in,
                              void* d_out, int out_size, void* d_ws, size_t ws_size,
                              hipStream_t stream) {
    const float* x      = (const float*)d_in[0];
    const float* gammas = (const float*)d_in[1];
    const float* betas  = (const float*)d_in[2];
    const float* wq     = (const float*)d_in[3];
    const float* wk     = (const float*)d_in[4];
    const float* wv     = (const float*)d_in[5];
    const float* wo     = (const float*)d_in[6];
    const float* bo     = (const float*)d_in[7];
    const float* w1     = (const float*)d_in[8];
    const float* b1     = (const float*)d_in[9];
    const float* w2     = (const float*)d_in[10];
    const float* b2     = (const float*)d_in[11];
    const int*   mask   = (const int*)d_in[12];
    float* out = (float*)d_out;

    // ---- workspace layout (bytes); peak ~40.5 MB ----
    char* wsb = (char*)d_ws;
    u16*   h1b   = (u16*)(wsb + 0);                 // 4 MB; LN1 out; then attnb/f1b
    u16*   kc    = (u16*)(wsb + (4ull  << 20));     // 4 MB compacted K (qkv epilogue scatter)
    u16*   vc    = (u16*)(wsb + (8ull  << 20));     // 4 MB compacted V
    u16*   vTc   = (u16*)(wsb + (12ull << 20));     // 4 MB compacted V^T
    u16*   qb    = (u16*)(wsb + (16ull << 20));     // 4 MB; reused as h2b
    u16*   Opart = (u16*)(wsb + (20ull << 20));     // 12 MB: 3 splits x 4 MB (20-32)
    u16*   x2b   = (u16*)(wsb + (20ull << 20));     // 4 MB bf16 x2 (over dead Opart)
    u16*   wqkvT = (u16*)(wsb + (32ull << 20));     // 1.5 MB
    u16*   woT   = wqkvT + 1536 * 512;              // 0.5 MB
    u16*   w1T   = woT   + 512 * 512;               // 2 MB
    u16*   w2T   = w1T   + 2048 * 512;              // 2 MB (ends 38 MB)
    float* maskc = (float*)(wsb + (38ull << 20));   // 16 KB
    int*   invidx= (int*)(wsb + (38ull << 20) + (64 << 10));   // 16 KB
    int*   nkp   = (int*)(wsb + (38ull << 20) + (128 << 10));  // 4 B
    float* ct    = (float*)(wsb + (39ull << 20));   // 256 KB
    float* st    = ct + 65536;                      // 256 KB
    float* lpart = (float*)(wsb + (40ull << 20));   // 384 KB
    u16*   f1b   = h1b;                             // 16 MB spanning slots 0-3 (FFN phase)
    u16*   h2b   = qb;
    u16*   attnb = h1b;

    // 0. fused prep: LN1 + mask scan (invidx) + rope tables + weight converts
    prep_kernel<<<SEQ / 4 + 1 + 256 + 3072, 256, 0, stream>>>(
        x, h1b, gammas, betas, wq, wk, wv, wo, w1, w2,
        wqkvT, woT, w1T, w2T, mask, maskc, invidx, nkp, ct, st);
    // 1. fused QKV projection + RoPE; 64x128 tiles (768 blocks = 3/CU exact, balanced)
    gemm_qkv<<<dim3(1536 / 128, SEQ / 64), 256, 0, stream>>>(
        h1b, wqkvT, qb, kc, vc, ct, st, invidx, SEQ, 1536, DIM);
    // 2. per-head transpose of compacted V (early-exit past last tile)
    transpose_c<<<dim3(SEQ / 64, NH), 256, 0, stream>>>(vc, nkp, vTc);
    // 3. attention over compacted keys, KV-split x3 (partials), then combine
    fattn_kernel<<<dim3(NH, SEQ / 128, KSPLIT), 256, 0, stream>>>(
        qb, kc, vTc, maskc, nkp, Opart, lpart);
    attn_combine<<<SEQ / 4, 256, 0, stream>>>(Opart, lpart, attnb);
    // 4. x2 = bf16(x + attn@wo + bo)  [x2b over dead Opart], BK=128
    gemm_bf16<1><<<dim3(DIM / 64, SEQ / 64), 256, 0, stream>>>(
        attnb, woT, bo, (const void*)x, x2b, SEQ, DIM, DIM, FLAG_BF16);
    // 5. h2 = LN(x2b) (bf16 in/out, wave-per-row)
    ln_bf16_kernel<<<SEQ / 4, 256, 0, stream>>>(x2b, h2b, gammas, betas, 1);
    // 6. f1 = gelu(h2@w1 + b1) (bf16), 128x128 tiles
    gemm128<<<dim3(FFD / 128, SEQ / 128), 256, 0, stream>>>(
        h2b, w1T, b1, f1b, SEQ, FFD, DIM, FLAG_BF16 | FLAG_GELU);
    // 7. out = x2b + f1@w2 + b2 (f32 out, bf16 resid), BK=128
    gemm_bf16<1><<<dim3(DIM / 64, SEQ / 64), 256, 0, stream>>>(
        f1b, w2T, b2, (const void*)x2b, out, SEQ, DIM, FFD, FLAG_RESID_BF16);
}

// Round 22
// 133.739 us; speedup vs baseline: 2.0016x; 1.0508x over previous
//
#include <hip/hip_runtime.h>
#include <math.h>

constexpr int SEQ  = 4096;
constexpr int DIM  = 512;
constexpr int NH   = 8;
constexpr int HDIM = 64;
constexpr int FFD  = 2048;
constexpr int KSPLIT = 3;

typedef unsigned short u16;
typedef __attribute__((ext_vector_type(8))) short bf16x8;
typedef __attribute__((ext_vector_type(4))) float f32x4;
typedef __attribute__((ext_vector_type(8))) unsigned short u16x8;

// score scale: (1/8) * log2(e), folded into wq. Softmax computed in exp2 domain.
// NO static shift: in compact key space all valid keys share mask=const, which
// cancels in the normalization; |s| <= ~1.2 so exp2 is overflow-safe. Only the
// tail-pad entries of the LAST tile carry -inf (exp2 -> exact 0).
#define LOG2E      1.4426950408889634f
#define QSCALE     (0.125f * LOG2E)
#define MASK_OFF   (-1.4427e9f)

static __device__ __forceinline__ u16 f2bf(float x) {
    union { float f; unsigned int u; } v; v.f = x;
    unsigned int r = v.u + 0x7fff + ((v.u >> 16) & 1);
    return (u16)(r >> 16);
}
static __device__ __forceinline__ float bf2f(u16 h) {
    union { unsigned int u; float f; } v; v.u = ((unsigned int)h) << 16;
    return v.f;
}
static __device__ __forceinline__ unsigned int cvtpk(float lo, float hi) {
    unsigned int r;
    asm volatile("v_cvt_pk_bf16_f32 %0, %1, %2" : "=v"(r) : "v"(lo), "v"(hi));
    return r;
}
static __device__ __forceinline__ float exp2f_fast(float x) {
    float r; asm volatile("v_exp_f32 %0, %1" : "=v"(r) : "v"(x)); return r;
}
static __device__ __forceinline__ void gload_lds16(const void* g, void* l) {
    __builtin_amdgcn_global_load_lds(
        (const __attribute__((address_space(1))) unsigned int*)g,
        (__attribute__((address_space(3))) unsigned int*)l, 16, 0, 0);
}

// ---------------- fused prep: LN1 (wave/row) + mask scan + rope tables + weight converts ----------------
__global__ void prep_kernel(const float* __restrict__ x, u16* __restrict__ h1,
                            const float* __restrict__ gammas, const float* __restrict__ betas,
                            const float* __restrict__ wq, const float* __restrict__ wk,
                            const float* __restrict__ wv, const float* __restrict__ wo,
                            const float* __restrict__ w1, const float* __restrict__ w2,
                            u16* __restrict__ wqkvT, u16* __restrict__ woT,
                            u16* __restrict__ w1T, u16* __restrict__ w2T,
                            const int* __restrict__ mask, float* __restrict__ maskc,
                            int* __restrict__ invidx, int* __restrict__ nkp,
                            float* __restrict__ ct, float* __restrict__ st) {
    __shared__ float smem[1056];
    int b = blockIdx.x;
    int t = threadIdx.x;
    if (b < SEQ / 4) {                          // LN1: 4 rows/block, one wave each, no LDS
        int wv_ = t >> 6, lane = t & 63;
        int row = b * 4 + wv_;
        const float* xr = x + (size_t)row * DIM + lane * 8;
        float4 a0 = *(const float4*)xr;
        float4 a1 = *(const float4*)(xr + 4);
        float f[8] = {a0.x, a0.y, a0.z, a0.w, a1.x, a1.y, a1.z, a1.w};
        float s = 0.f, qs = 0.f;
#pragma unroll
        for (int i = 0; i < 8; i++) { s += f[i]; qs += f[i] * f[i]; }
#pragma unroll
        for (int o = 1; o < 64; o <<= 1) {
            s  += __shfl_xor(s, o, 64);
            qs += __shfl_xor(qs, o, 64);
        }
        float mean = s / DIM;
        float var  = qs / DIM - mean * mean;
        float rstd = rsqrtf(var + 1e-5f);
        float g = gammas[0], be = betas[0];
        u16x8 res;
#pragma unroll
        for (int i = 0; i < 8; i += 2) {
            unsigned int pk = cvtpk(g * ((f[i] - mean) * rstd) + be,
                                    g * ((f[i + 1] - mean) * rstd) + be);
            res[i]     = (u16)(pk & 0xffff);
            res[i + 1] = (u16)(pk >> 16);
        }
        *(u16x8*)(h1 + (size_t)row * DIM + lane * 8) = res;
        return;
    }
    b -= SEQ / 4;
    if (b < 1) {                                // mask-compaction scan (1 block, 256 thr x 16)
        __shared__ int cnt[256];
        int base = t * 16;
        int loc[16]; int c = 0;
#pragma unroll
        for (int i = 0; i < 16; i++) { loc[i] = mask[base + i]; c += (loc[i] != 0); }
        cnt[t] = c;
        __syncthreads();
        for (int o = 1; o < 256; o <<= 1) {
            int v = (t >= o) ? cnt[t - o] : 0;
            __syncthreads();
            cnt[t] += v;
            __syncthreads();
        }
        int pos = cnt[t] - c;                   // exclusive prefix
        int total = cnt[255];
#pragma unroll
        for (int i = 0; i < 16; i++)
            invidx[base + i] = loc[i] ? pos++ : -1;
#pragma unroll
        for (int i = 0; i < 16; i++)
            maskc[base + i] = (base + i < total) ? 0.0f : MASK_OFF;
        if (t == 0) *nkp = total;
        return;
    }
    b -= 1;
    if (b < 256) {                              // rope cos/sin tables: [s][i], i<16
        int idx = b * 256 + t;                  // 65536 = 4096*16
        int s = idx >> 4, i = idx & 15;
        float invf = expf(-(float)i * (9.2103403719761836f / 16.0f));  // 10000^(-i/16)
        float freq = (float)s * invf;
        ct[idx] = cosf(freq);
        st[idx] = sinf(freq);
        return;
    }
    b -= 256;
    const float* src; u16* dst; int K, N; float scale = 1.f;
    if (b < 256)       { src = wq; dst = wqkvT;            K = 512;  N = 512; scale = QSCALE; }
    else if (b < 512)  { src = wk; dst = wqkvT + 512*512;  K = 512;  N = 512; b -= 256; }
    else if (b < 768)  { src = wv; dst = wqkvT + 1024*512; K = 512;  N = 512; b -= 512; }
    else if (b < 1024) { src = wo; dst = woT;              K = 512;  N = 512; b -= 768; }
    else if (b < 2048) { src = w1; dst = w1T;              K = 512;  N = 2048; b -= 1024; }
    else               { src = w2; dst = w2T;              K = 2048; N = 512;  b -= 2048; }
    float (*tile)[33] = (float(*)[33])smem;
    int tiles_x = N / 32;
    int n0 = (b % tiles_x) * 32, k0 = (b / tiles_x) * 32;
    int tx = t & 31, ty = t >> 5;               // 32 x 8
#pragma unroll
    for (int i = 0; i < 4; i++) {
        int kk = ty + i * 8;
        tile[kk][tx] = src[(size_t)(k0 + kk) * N + n0 + tx];
    }
    __syncthreads();
#pragma unroll
    for (int i = 0; i < 4; i++) {
        int nn = ty + i * 8;
        dst[(size_t)(n0 + nn) * K + k0 + tx] = f2bf(scale * tile[tx][nn]);
    }
}

// ---------------- LayerNorm LN2, bf16 in/out, wave-per-row ----------------
__global__ void ln_bf16_kernel(const u16* __restrict__ x, u16* __restrict__ out,
                               const float* __restrict__ gammas, const float* __restrict__ betas,
                               int gi) {
    int t = threadIdx.x;
    int wv_ = t >> 6, lane = t & 63;
    int row = blockIdx.x * 4 + wv_;
    u16x8 v = *(const u16x8*)(x + (size_t)row * DIM + lane * 8);
    float f[8];
    float s = 0.f, qs = 0.f;
#pragma unroll
    for (int i = 0; i < 8; i++) { f[i] = bf2f(v[i]); s += f[i]; qs += f[i] * f[i]; }
#pragma unroll
    for (int o = 1; o < 64; o <<= 1) {
        s  += __shfl_xor(s, o, 64);
        qs += __shfl_xor(qs, o, 64);
    }
    float mean = s / DIM;
    float var  = qs / DIM - mean * mean;
    float rstd = rsqrtf(var + 1e-5f);
    float g = gammas[gi], be = betas[gi];
    u16x8 res;
#pragma unroll
    for (int i = 0; i < 8; i += 2) {
        unsigned int pk = cvtpk(g * ((f[i] - mean) * rstd) + be,
                                g * ((f[i + 1] - mean) * rstd) + be);
        res[i]     = (u16)(pk & 0xffff);
        res[i + 1] = (u16)(pk >> 16);
    }
    *(u16x8*)(out + (size_t)row * DIM + lane * 8) = res;
}

constexpr int FLAG_BF16 = 1, FLAG_GELU = 2, FLAG_SPLIT = 4, FLAG_ROPE = 8, FLAG_RESID_BF16 = 16;

// ---------------- bf16 MFMA GEMM, 64-wide tiles, BK=128 (wo): C = A @ WT^T ----------------
template<int MF>
__global__ __launch_bounds__(256) void gemm_bf16(
    const u16* __restrict__ A, const u16* __restrict__ WT,
    const float* __restrict__ bias, const void* __restrict__ resid,
    void* __restrict__ Cq, int M, int N, int K, int flags)
{
    constexpr int BM = MF * 64;
    __shared__ __align__(16) u16 At[2][BM * 128];
    __shared__ __align__(16) u16 Bt[2][64 * 128];
    const int t = threadIdx.x, lane = t & 63, w = t >> 6;
    const int n0 = blockIdx.x * 64, m0 = blockIdx.y * BM;
    const int l15 = lane & 15, l4 = lane >> 4;

    f32x4 acc[MF][4];
#pragma unroll
    for (int m = 0; m < MF; m++)
#pragma unroll
        for (int n = 0; n < 4; n++) acc[m][n] = (f32x4){0.f, 0.f, 0.f, 0.f};

    auto stage = [&](int buf, int k0) {
#pragma unroll
        for (int i = 0; i < MF * 4; i++) {       // A: BM rows x 16 chunks
            int c = (w * MF * 4 + i) * 64 + lane;
            int r = c >> 4, jj = (c & 15) ^ (r & 7);
            gload_lds16(A + (size_t)(m0 + r) * K + k0 + jj * 8,
                        (char*)At[buf] + (w * MF * 4 + i) * 1024);
        }
#pragma unroll
        for (int i = 0; i < 4; i++) {            // B: 64 rows x 16 chunks
            int c = (w * 4 + i) * 64 + lane;
            int r = c >> 4, jj = (c & 15) ^ (r & 7);
            gload_lds16(WT + (size_t)(n0 + r) * K + k0 + jj * 8,
                        (char*)Bt[buf] + (w * 4 + i) * 1024);
        }
    };

    const int NT = K / 128;
    stage(0, 0);
    for (int ti = 0; ti < NT; ti++) {
        const int cur = ti & 1;
        asm volatile("s_waitcnt vmcnt(0)" ::: "memory");
        __syncthreads();
        if (ti + 1 < NT) stage(cur ^ 1, (ti + 1) * 128);
        __builtin_amdgcn_s_setprio(1);
#pragma unroll
        for (int kk = 0; kk < 4; kk++) {
            bf16x8 af[MF], bfr[4];
#pragma unroll
            for (int m = 0; m < MF; m++) {
                int row = w * MF * 16 + m * 16 + l15;
                af[m] = *(bf16x8*)((char*)At[cur] + row * 256 +
                                   ((kk * 64 + l4 * 16) ^ ((row & 7) << 4)));
            }
#pragma unroll
            for (int n = 0; n < 4; n++) {
                int row = n * 16 + l15;
                bfr[n] = *(bf16x8*)((char*)Bt[cur] + row * 256 +
                                    ((kk * 64 + l4 * 16) ^ ((row & 7) << 4)));
            }
#pragma unroll
            for (int m = 0; m < MF; m++)
#pragma unroll
                for (int n = 0; n < 4; n++)
                    acc[m][n] = __builtin_amdgcn_mfma_f32_16x16x32_bf16(
                        af[m], bfr[n], acc[m][n], 0, 0, 0);
        }
        __builtin_amdgcn_s_setprio(0);
    }

#pragma unroll
    for (int m = 0; m < MF; m++)
#pragma unroll
        for (int rr = 0; rr < 4; rr++) {
            int row = m0 + w * MF * 16 + m * 16 + l4 * 4 + rr;
#pragma unroll
            for (int n = 0; n < 4; n++) {
                int colg = n0 + n * 16 + l15;
                float cv = acc[m][n][rr];
                if (bias) cv += bias[colg];
                if (flags & FLAG_GELU) cv = 0.5f * cv * (1.0f + erff(cv * 0.70710678118f));
                if (resid) {
                    if (flags & FLAG_RESID_BF16)
                        cv += bf2f(((const u16*)resid)[(size_t)row * N + colg]);
                    else
                        cv += ((const float*)resid)[(size_t)row * N + colg];
                }
                if (flags & FLAG_BF16) {
                    ((u16*)Cq)[(size_t)row * N + colg] = f2bf(cv);
                } else {
                    ((float*)Cq)[(size_t)row * N + colg] = cv;
                }
            }
        }
}

// ---------------- bf16 MFMA GEMM, 64x128 tile (qkv): 3 blocks/CU exact, balanced ----------------
__global__ __launch_bounds__(256, 3) void gemm_qkv(
    const u16* __restrict__ A, const u16* __restrict__ WT,
    void* __restrict__ Cq, void* __restrict__ Ck, void* __restrict__ Cv,
    const float* __restrict__ ct, const float* __restrict__ st,
    const int* __restrict__ invidx,
    int M, int N, int K)
{
    __shared__ __align__(16) u16 At[2][64 * 64];    //  8 KB per buf
    __shared__ __align__(16) u16 Bt[2][128 * 64];   // 16 KB per buf
    const int t = threadIdx.x, lane = t & 63, w = t >> 6;
    const int wm = w >> 1, wn = w & 1;
    const int n0 = blockIdx.x * 128, m0 = blockIdx.y * 64;
    const int l15 = lane & 15, l4 = lane >> 4;

    f32x4 acc[2][4];
#pragma unroll
    for (int m = 0; m < 2; m++)
#pragma unroll
        for (int n = 0; n < 4; n++) acc[m][n] = (f32x4){0.f, 0.f, 0.f, 0.f};

    auto stage = [&](int buf, int k0) {
#pragma unroll
        for (int i = 0; i < 2; i++) {            // A: 64 rows x 8 chunks = 512
            int c = (w * 2 + i) * 64 + lane;
            int r = c >> 3, j = (c & 7) ^ (r & 7);
            gload_lds16(A + (size_t)(m0 + r) * K + k0 + j * 8,
                        (char*)At[buf] + (w * 2 + i) * 1024);
        }
#pragma unroll
        for (int i = 0; i < 4; i++) {            // B: 128 rows x 8 chunks = 1024
            int c = (w * 4 + i) * 64 + lane;
            int r = c >> 3, j = (c & 7) ^ (r & 7);
            gload_lds16(WT + (size_t)(n0 + r) * K + k0 + j * 8,
                        (char*)Bt[buf] + (w * 4 + i) * 1024);
        }
    };

    const int NT = K / 64;
    stage(0, 0);
    for (int ti = 0; ti < NT; ti++) {
        const int cur = ti & 1;
        asm volatile("s_waitcnt vmcnt(0)" ::: "memory");
        __syncthreads();
        if (ti + 1 < NT) stage(cur ^ 1, (ti + 1) * 64);
        __builtin_amdgcn_s_setprio(1);
#pragma unroll
        for (int kk = 0; kk < 2; kk++) {
            bf16x8 af[2], bfr[4];
#pragma unroll
            for (int m = 0; m < 2; m++) {
                int row = wm * 32 + m * 16 + l15;
                af[m] = *(bf16x8*)((char*)At[cur] + row * 128 +
                                   ((kk * 64 + l4 * 16) ^ ((row & 7) << 4)));
            }
#pragma unroll
            for (int n = 0; n < 4; n++) {
                int row = wn * 64 + n * 16 + l15;
                bfr[n] = *(bf16x8*)((char*)Bt[cur] + row * 128 +
                                    ((kk * 64 + l4 * 16) ^ ((row & 7) << 4)));
            }
#pragma unroll
            for (int m = 0; m < 2; m++)
#pragma unroll
                for (int n = 0; n < 4; n++)
                    acc[m][n] = __builtin_amdgcn_mfma_f32_16x16x32_bf16(
                        af[m], bfr[n], acc[m][n], 0, 0, 0);
        }
        __builtin_amdgcn_s_setprio(0);
    }

    // epilogue: rope on q/k head-cols < 32, split-scatter K/V to compacted slots
    const int which = (n0 + wn * 64) >> 9;      // constant per wave (128 | 512)
#pragma unroll
    for (int m = 0; m < 2; m++)
#pragma unroll
        for (int rr = 0; rr < 4; rr++) {
            int row = m0 + wm * 32 + m * 16 + l4 * 4 + rr;
            int orow = (which > 0) ? invidx[row] : row;
#pragma unroll
            for (int n = 0; n < 4; n++) {
                int colg = n0 + wn * 64 + n * 16 + l15;
                float cv = acc[m][n][rr];
                if (which < 2 && n < 2) {        // RoPE (head-col = n*16+l15 < 32)
                    float partner = __shfl_xor(cv, 1, 64);
                    int i = (n * 16 + l15) >> 1;
                    float cc = ct[row * 16 + i], ss = st[row * 16 + i];
                    cv = (l15 & 1) ? (cv * cc + partner * ss) : (cv * cc - partner * ss);
                }
                if (orow >= 0) {
                    u16* dst = which == 0 ? (u16*)Cq : which == 1 ? (u16*)Ck : (u16*)Cv;
                    dst[(size_t)orow * 512 + (colg & 511)] = f2bf(cv);
                }
            }
        }
}

// ---------------- bf16 MFMA GEMM, 128x128 tile (ffn1) ----------------
__global__ __launch_bounds__(256) void gemm128(
    const u16* __restrict__ A, const u16* __restrict__ WT,
    const float* __restrict__ bias,
    void* __restrict__ Cq,
    int M, int N, int K, int flags)
{
    __shared__ __align__(16) u16 At[2][128 * 64];   // 16 KB per buf, swizzled image
    __shared__ __align__(16) u16 Bt[2][128 * 64];
    const int t = threadIdx.x, lane = t & 63, w = t >> 6;
    const int wm = w >> 1, wn = w & 1;
    const int n0 = blockIdx.x * 128, m0 = blockIdx.y * 128;
    const int l15 = lane & 15, l4 = lane >> 4;

    f32x4 acc[4][4];
#pragma unroll
    for (int m = 0; m < 4; m++)
#pragma unroll
        for (int n = 0; n < 4; n++) acc[m][n] = (f32x4){0.f, 0.f, 0.f, 0.f};

    auto stage = [&](int buf, int k0) {
#pragma unroll
        for (int i = 0; i < 4; i++) {
            int c = (w * 4 + i) * 64 + lane;
            int r = c >> 3, j = (c & 7) ^ (r & 7);
            gload_lds16(A + (size_t)(m0 + r) * K + k0 + j * 8,
                        (char*)At[buf] + (w * 4 + i) * 1024);
            gload_lds16(WT + (size_t)(n0 + r) * K + k0 + j * 8,
                        (char*)Bt[buf] + (w * 4 + i) * 1024);
        }
    };

    const int NT = K / 64;
    stage(0, 0);
    for (int ti = 0; ti < NT; ti++) {
        const int cur = ti & 1;
        asm volatile("s_waitcnt vmcnt(0)" ::: "memory");
        __syncthreads();
        if (ti + 1 < NT) stage(cur ^ 1, (ti + 1) * 64);
        __builtin_amdgcn_s_setprio(1);
#pragma unroll
        for (int kk = 0; kk < 2; kk++) {
            bf16x8 af[4], bfr[4];
#pragma unroll
            for (int m = 0; m < 4; m++) {
                int row = wm * 64 + m * 16 + l15;
                af[m] = *(bf16x8*)((char*)At[cur] + row * 128 +
                                   ((kk * 64 + l4 * 16) ^ ((row & 7) << 4)));
            }
#pragma unroll
            for (int n = 0; n < 4; n++) {
                int row = wn * 64 + n * 16 + l15;
                bfr[n] = *(bf16x8*)((char*)Bt[cur] + row * 128 +
                                    ((kk * 64 + l4 * 16) ^ ((row & 7) << 4)));
            }
#pragma unroll
            for (int m = 0; m < 4; m++)
#pragma unroll
                for (int n = 0; n < 4; n++)
                    acc[m][n] = __builtin_amdgcn_mfma_f32_16x16x32_bf16(
                        af[m], bfr[n], acc[m][n], 0, 0, 0);
        }
        __builtin_amdgcn_s_setprio(0);
    }

    // epilogue (bias / gelu / bf16)
#pragma unroll
    for (int m = 0; m < 4; m++)
#pragma unroll
        for (int rr = 0; rr < 4; rr++) {
            int row = m0 + wm * 64 + m * 16 + l4 * 4 + rr;
#pragma unroll
            for (int n = 0; n < 4; n++) {
                int colg = n0 + wn * 64 + n * 16 + l15;
                float cv = acc[m][n][rr];
                if (bias) cv += bias[colg];
                if (flags & FLAG_GELU) cv = 0.5f * cv * (1.0f + erff(cv * 0.70710678118f));
                ((u16*)Cq)[(size_t)row * N + colg] = f2bf(cv);
            }
        }
}

// ---------------- w2 split-K GEMM: 128x128 tile, 4 K-splits, bf16 partials ----------------
// Grid (N/128=4, M/128=32, 4) = 512 blocks @ 64 KB = 2/CU exact, balanced.
// Each split z covers K in [z*512, (z+1)*512); partial written to pz (no bias/resid).
__global__ __launch_bounds__(256) void gemm_w2split(
    const u16* __restrict__ A, const u16* __restrict__ WT,
    u16* __restrict__ p0, u16* __restrict__ p1,
    u16* __restrict__ p2, u16* __restrict__ p3,
    int M, int N, int K)
{
    __shared__ __align__(16) u16 At[2][128 * 64];
    __shared__ __align__(16) u16 Bt[2][128 * 64];
    const int t = threadIdx.x, lane = t & 63, w = t >> 6;
    const int wm = w >> 1, wn = w & 1;
    const int n0 = blockIdx.x * 128, m0 = blockIdx.y * 128;
    const int z = blockIdx.z;
    const int kbase = z * (K / 4);
    const int l15 = lane & 15, l4 = lane >> 4;

    f32x4 acc[4][4];
#pragma unroll
    for (int m = 0; m < 4; m++)
#pragma unroll
        for (int n = 0; n < 4; n++) acc[m][n] = (f32x4){0.f, 0.f, 0.f, 0.f};

    auto stage = [&](int buf, int k0) {
#pragma unroll
        for (int i = 0; i < 4; i++) {
            int c = (w * 4 + i) * 64 + lane;
            int r = c >> 3, j = (c & 7) ^ (r & 7);
            gload_lds16(A + (size_t)(m0 + r) * K + k0 + j * 8,
                        (char*)At[buf] + (w * 4 + i) * 1024);
            gload_lds16(WT + (size_t)(n0 + r) * K + k0 + j * 8,
                        (char*)Bt[buf] + (w * 4 + i) * 1024);
        }
    };

    const int NT = (K / 4) / 64;                // 8
    stage(0, kbase);
    for (int ti = 0; ti < NT; ti++) {
        const int cur = ti & 1;
        asm volatile("s_waitcnt vmcnt(0)" ::: "memory");
        __syncthreads();
        if (ti + 1 < NT) stage(cur ^ 1, kbase + (ti + 1) * 64);
        __builtin_amdgcn_s_setprio(1);
#pragma unroll
        for (int kk = 0; kk < 2; kk++) {
            bf16x8 af[4], bfr[4];
#pragma unroll
            for (int m = 0; m < 4; m++) {
                int row = wm * 64 + m * 16 + l15;
                af[m] = *(bf16x8*)((char*)At[cur] + row * 128 +
                                   ((kk * 64 + l4 * 16) ^ ((row & 7) << 4)));
            }
#pragma unroll
            for (int n = 0; n < 4; n++) {
                int row = wn * 64 + n * 16 + l15;
                bfr[n] = *(bf16x8*)((char*)Bt[cur] + row * 128 +
                                    ((kk * 64 + l4 * 16) ^ ((row & 7) << 4)));
            }
#pragma unroll
            for (int m = 0; m < 4; m++)
#pragma unroll
                for (int n = 0; n < 4; n++)
                    acc[m][n] = __builtin_amdgcn_mfma_f32_16x16x32_bf16(
                        af[m], bfr[n], acc[m][n], 0, 0, 0);
        }
        __builtin_amdgcn_s_setprio(0);
    }

    u16* pz = (z == 0) ? p0 : (z == 1) ? p1 : (z == 2) ? p2 : p3;
#pragma unroll
    for (int m = 0; m < 4; m++)
#pragma unroll
        for (int rr = 0; rr < 4; rr++) {
            int row = m0 + wm * 64 + m * 16 + l4 * 4 + rr;
#pragma unroll
            for (int n = 0; n < 4; n++) {
                int colg = n0 + wn * 64 + n * 16 + l15;
                pz[(size_t)row * N + colg] = f2bf(acc[m][n][rr]);
            }
        }
}

// ---------------- w2 combine: out = x2b + p0+p1+p2+p3 + b2 (f32 out) ----------------
__global__ void w2_combine(const u16* __restrict__ p0, const u16* __restrict__ p1,
                           const u16* __restrict__ p2, const u16* __restrict__ p3,
                           const u16* __restrict__ x2b, const float* __restrict__ b2,
                           float* __restrict__ out) {
    int t = threadIdx.x;               // 256 threads = 4 rows x 64 col-groups of 8
    int row = blockIdx.x * 4 + (t >> 6);
    int col = (t & 63) * 8;
    size_t off = (size_t)row * DIM + col;
    u16x8 a = *(const u16x8*)(p0 + off);
    u16x8 b = *(const u16x8*)(p1 + off);
    u16x8 c = *(const u16x8*)(p2 + off);
    u16x8 d = *(const u16x8*)(p3 + off);
    u16x8 xr = *(const u16x8*)(x2b + off);
    float4 bb0 = *(const float4*)(b2 + col);
    float4 bb1 = *(const float4*)(b2 + col + 4);
    float bias[8] = {bb0.x, bb0.y, bb0.z, bb0.w, bb1.x, bb1.y, bb1.z, bb1.w};
    float res[8];
#pragma unroll
    for (int j = 0; j < 8; j++)
        res[j] = bf2f(xr[j]) + bf2f(a[j]) + bf2f(b[j]) + bf2f(c[j]) + bf2f(d[j]) + bias[j];
    *(float4*)(out + off)     = (float4){res[0], res[1], res[2], res[3]};
    *(float4*)(out + off + 4) = (float4){res[4], res[5], res[6], res[7]};
}

// ---------------- per-head transpose of compacted V: vc (nk, NH*HD) -> vTc (NH, HD, SEQ) ----------------
__global__ void transpose_c(const u16* __restrict__ vc, const int* __restrict__ nkp,
                            u16* __restrict__ vTc) {
    int nk = *nkp;
    int s0 = blockIdx.x * 64;
    if (s0 >= ((nk + 63) & ~63)) return;        // past last compacted tile
    __shared__ __align__(16) u16 tile[64][80];
    int h = blockIdx.y;
    int t = threadIdx.x;               // 256
#pragma unroll
    for (int p = 0; p < 2; p++) {
        int c = p * 256 + t;
        int r = c >> 3, j = c & 7;
        u16x8 vv = {};
        if (s0 + r < nk)
            vv = *(const u16x8*)(vc + (size_t)(s0 + r) * DIM + h * HDIM + j * 8);
        *(u16x8*)&tile[r][j * 8] = vv;
    }
    __syncthreads();
#pragma unroll
    for (int p = 0; p < 2; p++) {
        int c = p * 256 + t;
        int d = c >> 3, j = c & 7;
        u16x8 vv;
#pragma unroll
        for (int i = 0; i < 8; i++) vv[i] = tile[j * 8 + i][d];
        *(u16x8*)(vTc + ((size_t)h * HDIM + d) * SEQ + s0 + j * 8) = vv;
    }
}

// ---------------- flash attention over COMPACTED keys: 32 q/wave, KV-split x3, LDS-P ----------------
__global__ __launch_bounds__(256, 3) void fattn_kernel(
    const u16* __restrict__ q, const u16* __restrict__ k,
    const u16* __restrict__ vT, const float* __restrict__ maskc,
    const int* __restrict__ nkp,
    u16* __restrict__ Opart, float* __restrict__ lpart)
{
    __shared__ __align__(16) u16 k_s[2][64 * 64];     // 16 KB [buf][key][d] swizzled image
    __shared__ __align__(16) u16 vt_s[2][64 * 64];    // 16 KB [buf][d][key] swizzled image
    __shared__ __align__(16) u16 p_s[4][32 * 64];     // 16 KB per-wave [q][key] swizzled

    const int t = threadIdx.x;
    const int lane = t & 63;
    const int w = t >> 6;
    const int h = blockIdx.x;
    const int q0 = blockIdx.y * 128;
    const int split = blockIdx.z;
    const int nk = *nkp;
    const int ntiles = (nk + 63) >> 6;
    const int tstart = (split * ntiles) / 3;
    const int tend   = ((split + 1) * ntiles) / 3;
    const int l15 = lane & 15, g = lane >> 4;

    // Q as B-frags, straight from global: q-row = q0+w*32+qh*16+l15, d = g*8+j (+32)
    bf16x8 qf[2][2];
#pragma unroll
    for (int qh = 0; qh < 2; qh++) {
        const u16* qrow = q + (size_t)(q0 + w * 32 + qh * 16 + l15) * DIM + h * HDIM;
        qf[qh][0] = *(const bf16x8*)(qrow + g * 8);
        qf[qh][1] = *(const bf16x8*)(qrow + g * 8 + 32);
    }

    // ones A-fragment (bf16 1.0 = 0x3F80) for the row-sum MFMA
    const bf16x8 ones = (bf16x8){16256, 16256, 16256, 16256, 16256, 16256, 16256, 16256};

    f32x4 O[2][4];                    // O^T: [qh][dt], reg r -> d = dt*16+4g+r, col q
    f32x4 lacc[2];                    // row-sum accumulator (all regs equal)
#pragma unroll
    for (int qh = 0; qh < 2; qh++) {
#pragma unroll
        for (int dt = 0; dt < 4; dt++) O[qh][dt] = (f32x4){0.f, 0.f, 0.f, 0.f};
        lacc[qh] = (f32x4){0.f, 0.f, 0.f, 0.f};
    }

    char* pbase = (char*)p_s[w];
    const int psw = (l15 & 7) << 4;

    auto stage = [&](int buf, int kb2) {
#pragma unroll
        for (int i = 0; i < 2; i++) {
            int c = (w * 2 + i) * 64 + lane;
            int r = c >> 3, j = (c & 7) ^ (r & 7);
            gload_lds16(k + (size_t)(kb2 + r) * DIM + h * HDIM + j * 8,
                        (char*)k_s + buf * 8192 + (w * 2 + i) * 1024);
            gload_lds16(vT + ((size_t)h * HDIM + r) * SEQ + kb2 + j * 8,
                        (char*)vt_s + buf * 8192 + (w * 2 + i) * 1024);
        }
    };

    if (tstart < tend) stage(0, tstart * 64);
    for (int ti = tstart; ti < tend; ti++) {
        const int cur = (ti - tstart) & 1;
        const int kb = ti * 64;
        asm volatile("s_waitcnt vmcnt(0)" ::: "memory");
        __syncthreads();
        if (ti + 1 < tend) stage(cur ^ 1, kb + 64);

        char* kcur = (char*)k_s + cur * 8192;
        char* vcur = (char*)vt_s + cur * 8192;

        // ---- QK^T (swapped): 2 independent chains (qh) off shared K A-frags ----
        f32x4 sacc[2][4];
        __builtin_amdgcn_s_setprio(1);
#pragma unroll
        for (int kt = 0; kt < 4; kt++) {
            int key = kt * 16 + l15;
            int ksw = (key & 7) << 4;
            char* kbase = kcur + key * 128;
            bf16x8 a0 = *(bf16x8*)(kbase + ((g * 16)      ^ ksw));
            bf16x8 a1 = *(bf16x8*)(kbase + ((g * 16 + 64) ^ ksw));
#pragma unroll
            for (int qh = 0; qh < 2; qh++) {
                f32x4 z = (f32x4){0.f, 0.f, 0.f, 0.f};
                z = __builtin_amdgcn_mfma_f32_16x16x32_bf16(a0, qf[qh][0], z, 0, 0, 0);
                z = __builtin_amdgcn_mfma_f32_16x16x32_bf16(a1, qf[qh][1], z, 0, 0, 0);
                sacc[qh][kt] = z;
            }
        }
        __builtin_amdgcn_s_setprio(0);

        // ---- P = exp2(sacc) [+pad mask only on the LAST tile] + b64 pack ----
        const bool haspad = (ti == ntiles - 1);
        if (!haspad) {
#pragma unroll
            for (int qh = 0; qh < 2; qh++)
#pragma unroll
                for (int kt = 0; kt < 4; kt++) {
                    float p0 = exp2f_fast(sacc[qh][kt][0]);
                    float p1 = exp2f_fast(sacc[qh][kt][1]);
                    float p2 = exp2f_fast(sacc[qh][kt][2]);
                    float p3 = exp2f_fast(sacc[qh][kt][3]);
                    uint2 pk;
                    pk.x = cvtpk(p0, p1);
                    pk.y = cvtpk(p2, p3);
                    int colb = (kt * 16 + g * 4) * 2;      // byte col, 8B aligned
                    *(uint2*)(pbase + (qh * 16 + l15) * 128 + (colb ^ psw)) = pk;
                }
        } else {
            float4 mf4[4];
#pragma unroll
            for (int kt = 0; kt < 4; kt++)
                mf4[kt] = *(const float4*)(maskc + kb + kt * 16 + g * 4);
#pragma unroll
            for (int qh = 0; qh < 2; qh++)
#pragma unroll
                for (int kt = 0; kt < 4; kt++) {
                    float p0 = exp2f_fast(sacc[qh][kt][0] + mf4[kt].x);
                    float p1 = exp2f_fast(sacc[qh][kt][1] + mf4[kt].y);
                    float p2 = exp2f_fast(sacc[qh][kt][2] + mf4[kt].z);
                    float p3 = exp2f_fast(sacc[qh][kt][3] + mf4[kt].w);
                    uint2 pk;
                    pk.x = cvtpk(p0, p1);
                    pk.y = cvtpk(p2, p3);
                    int colb = (kt * 16 + g * 4) * 2;
                    *(uint2*)(pbase + (qh * 16 + l15) * 128 + (colb ^ psw)) = pk;
                }
        }

        // ---- PV: O^T += V^T(A) @ P(B); lacc += ones @ P (row sums) ----
        __builtin_amdgcn_s_setprio(1);
#pragma unroll
        for (int h2 = 0; h2 < 2; h2++) {
            bf16x8 pb[2];
#pragma unroll
            for (int qh = 0; qh < 2; qh++)
                pb[qh] = *(bf16x8*)(pbase + (qh * 16 + l15) * 128 +
                                    (((h2 * 4 + g) * 16) ^ psw));
#pragma unroll
            for (int dt = 0; dt < 4; dt++) {
                int d = dt * 16 + l15;
                bf16x8 va = *(bf16x8*)(vcur + d * 128 +
                                       (((h2 * 4 + g) * 16) ^ ((d & 7) << 4)));
#pragma unroll
                for (int qh = 0; qh < 2; qh++)
                    O[qh][dt] = __builtin_amdgcn_mfma_f32_16x16x32_bf16(
                        va, pb[qh], O[qh][dt], 0, 0, 0);
            }
#pragma unroll
            for (int qh = 0; qh < 2; qh++)
                lacc[qh] = __builtin_amdgcn_mfma_f32_16x16x32_bf16(
                    ones, pb[qh], lacc[qh], 0, 0, 0);
        }
        __builtin_amdgcn_s_setprio(0);
    }

    // ---- epilogue: unnormalized partial O (bf16) + partial row sums ----
#pragma unroll
    for (int qh = 0; qh < 2; qh++) {
        float lrun = lacc[qh][0];     // every lane holds the full sum for its q-col
        int row = q0 + w * 32 + qh * 16 + l15;
        u16* orow = Opart + (size_t)split * SEQ * DIM + (size_t)row * DIM + h * HDIM;
#pragma unroll
        for (int dt = 0; dt < 4; dt++)
#pragma unroll
            for (int r = 0; r < 4; r += 2) {
                unsigned int pk = cvtpk(O[qh][dt][r], O[qh][dt][r + 1]);
                *(unsigned int*)(orow + dt * 16 + 4 * g + r) = pk;
            }
        if (g == 0)
            lpart[((size_t)split * NH + h) * SEQ + row] = lrun;
    }
}

// ---------------- combine: out = (O0+O1+O2) / (l0+l1+l2), bf16, u16x8 vectorized ----------------
__global__ void attn_combine(const u16* __restrict__ Opart, const float* __restrict__ lpart,
                             u16* __restrict__ out) {
    int t = threadIdx.x;               // 256 threads = 4 rows x 64 col-groups
    int row = blockIdx.x * 4 + (t >> 6);
    int col = (t & 63) * 8;
    int h = col >> 6;
    float l = lpart[(size_t)h * SEQ + row]
            + lpart[((size_t)NH + h) * SEQ + row]
            + lpart[((size_t)2 * NH + h) * SEQ + row];
    float inv = 1.0f / l;
    const size_t SD = (size_t)SEQ * DIM;
    const u16* base = Opart + (size_t)row * DIM + col;
    u16x8 ua = *(const u16x8*)(base);
    u16x8 ub = *(const u16x8*)(base + SD);
    u16x8 uc = *(const u16x8*)(base + 2 * SD);
    u16x8 res;
#pragma unroll
    for (int j = 0; j < 8; j += 2) {
        float o0 = bf2f(ua[j])     + bf2f(ub[j])     + bf2f(uc[j]);
        float o1 = bf2f(ua[j + 1]) + bf2f(ub[j + 1]) + bf2f(uc[j + 1]);
        unsigned int pk = cvtpk(o0 * inv, o1 * inv);
        res[j]     = (u16)(pk & 0xffff);
        res[j + 1] = (u16)(pk >> 16);
    }
    *(u16x8*)(out + (size_t)row * DIM + col) = res;
}

extern "C" void kernel_launch(void* const* d_in, const int* in_sizes, int n_in,
                              void* d_out, int out_size, void* d_ws, size_t ws_size,
                              hipStream_t stream) {
    const float* x      = (const float*)d_in[0];
    const float* gammas = (const float*)d_in[1];
    const float* betas  = (const float*)d_in[2];
    const float* wq     = (const float*)d_in[3];
    const float* wk     = (const float*)d_in[4];
    const float* wv     = (const float*)d_in[5];
    const float* wo     = (const float*)d_in[6];
    const float* bo     = (const float*)d_in[7];
    const float* w1     = (const float*)d_in[8];
    const float* b1     = (const float*)d_in[9];
    const float* w2     = (const float*)d_in[10];
    const float* b2     = (const float*)d_in[11];
    const int*   mask   = (const int*)d_in[12];
    float* out = (float*)d_out;

    // ---- workspace layout (bytes); peak ~45 MB (ws >= ~47 MB proven R8) ----
    char* wsb = (char*)d_ws;
    u16*   h1b   = (u16*)(wsb + 0);                 // 4 MB; LN1 out; then attnb; f1b spans 0-16
    u16*   kc    = (u16*)(wsb + (4ull  << 20));     // 4 MB compacted K
    u16*   vc    = (u16*)(wsb + (8ull  << 20));     // 4 MB compacted V
    u16*   vTc   = (u16*)(wsb + (12ull << 20));     // 4 MB compacted V^T
    u16*   qb    = (u16*)(wsb + (16ull << 20));     // 4 MB; reused as h2b; dead during w2 -> wp2
    u16*   Opart = (u16*)(wsb + (20ull << 20));     // 12 MB: 3 splits x 4 MB (20-32)
    u16*   x2b   = (u16*)(wsb + (20ull << 20));     // 4 MB bf16 x2 (over dead Opart; LIVE at end)
    u16*   wqkvT = (u16*)(wsb + (32ull << 20));     // 1.5 MB
    u16*   woT   = wqkvT + 1536 * 512;              // 0.5 MB
    u16*   w1T   = woT   + 512 * 512;               // 2 MB
    u16*   w2T   = w1T   + 2048 * 512;              // 2 MB (ends 38 MB)
    float* maskc = (float*)(wsb + (38ull << 20));   // 16 KB
    int*   invidx= (int*)(wsb + (38ull << 20) + (64 << 10));   // 16 KB
    int*   nkp   = (int*)(wsb + (38ull << 20) + (128 << 10));  // 4 B
    float* ct    = (float*)(wsb + (39ull << 20));   // 256 KB
    float* st    = ct + 65536;                      // 256 KB
    float* lpart = (float*)(wsb + (40ull << 20));   // 384 KB
    // w2 split-K partials (4 MB each), in regions dead during the FFN phase:
    u16*   wp0   = (u16*)(wsb + (24ull << 20));     // dead Opart tail
    u16*   wp1   = (u16*)(wsb + (28ull << 20));     // dead Opart tail
    u16*   wp2   = (u16*)(wsb + (16ull << 20));     // dead qb/h2b (after ffn1 reads h2b)
    u16*   wp3   = (u16*)(wsb + (41ull << 20));     // free tail (41-45 MB)
    u16*   f1b   = h1b;                             // 16 MB spanning slots 0-3 (FFN phase)
    u16*   h2b   = qb;
    u16*   attnb = h1b;

    // 0. fused prep: LN1 + mask scan (invidx) + rope tables + weight converts
    prep_kernel<<<SEQ / 4 + 1 + 256 + 3072, 256, 0, stream>>>(
        x, h1b, gammas, betas, wq, wk, wv, wo, w1, w2,
        wqkvT, woT, w1T, w2T, mask, maskc, invidx, nkp, ct, st);
    // 1. fused QKV projection + RoPE; 64x128 tiles (768 blocks = 3/CU exact, balanced)
    gemm_qkv<<<dim3(1536 / 128, SEQ / 64), 256, 0, stream>>>(
        h1b, wqkvT, qb, kc, vc, ct, st, invidx, SEQ, 1536, DIM);
    // 2. per-head transpose of compacted V (early-exit past last tile)
    transpose_c<<<dim3(SEQ / 64, NH), 256, 0, stream>>>(vc, nkp, vTc);
    // 3. attention over compacted keys, KV-split x3 (partials), then combine
    fattn_kernel<<<dim3(NH, SEQ / 128, KSPLIT), 256, 0, stream>>>(
        qb, kc, vTc, maskc, nkp, Opart, lpart);
    attn_combine<<<SEQ / 4, 256, 0, stream>>>(Opart, lpart, attnb);
    // 4. x2 = bf16(x + attn@wo + bo)  [x2b over dead Opart], BK=128
    gemm_bf16<1><<<dim3(DIM / 64, SEQ / 64), 256, 0, stream>>>(
        attnb, woT, bo, (const void*)x, x2b, SEQ, DIM, DIM, FLAG_BF16);
    // 5. h2 = LN(x2b) (bf16 in/out, wave-per-row)
    ln_bf16_kernel<<<SEQ / 4, 256, 0, stream>>>(x2b, h2b, gammas, betas, 1);
    // 6. f1 = gelu(h2@w1 + b1) (bf16), 128x128 tiles
    gemm128<<<dim3(FFD / 128, SEQ / 128), 256, 0, stream>>>(
        h2b, w1T, b1, f1b, SEQ, FFD, DIM, FLAG_BF16 | FLAG_GELU);
    // 7. w2 split-K x4 (128x128 tiles, 512 blocks = 2/CU exact), bf16 partials
    gemm_w2split<<<dim3(DIM / 128, SEQ / 128, 4), 256, 0, stream>>>(
        f1b, w2T, wp0, wp1, wp2, wp3, SEQ, DIM, FFD);
    // 8. out = x2b + sum(partials) + b2 (f32)
    w2_combine<<<SEQ / 4, 256, 0, stream>>>(wp0, wp1, wp2, wp3, x2b, b2, out);
}

// Round 23
// 130.816 us; speedup vs baseline: 2.0463x; 1.0223x over previous
//
#include <hip/hip_runtime.h>
#include <math.h>

constexpr int SEQ  = 4096;
constexpr int DIM  = 512;
constexpr int NH   = 8;
constexpr int HDIM = 64;
constexpr int FFD  = 2048;
constexpr int KSPLIT = 3;

typedef unsigned short u16;
typedef __attribute__((ext_vector_type(8))) short bf16x8;
typedef __attribute__((ext_vector_type(4))) float f32x4;
typedef __attribute__((ext_vector_type(8))) unsigned short u16x8;

// score scale: (1/8) * log2(e), folded into wq. Softmax computed in exp2 domain.
// NO static shift: in compact key space all valid keys share mask=const, which
// cancels in the normalization; |s| <= ~1.2 so exp2 is overflow-safe. Only the
// tail-pad entries of the LAST tile carry -inf (exp2 -> exact 0).
#define LOG2E      1.4426950408889634f
#define QSCALE     (0.125f * LOG2E)
#define MASK_OFF   (-1.4427e9f)

static __device__ __forceinline__ u16 f2bf(float x) {
    union { float f; unsigned int u; } v; v.f = x;
    unsigned int r = v.u + 0x7fff + ((v.u >> 16) & 1);
    return (u16)(r >> 16);
}
static __device__ __forceinline__ float bf2f(u16 h) {
    union { unsigned int u; float f; } v; v.u = ((unsigned int)h) << 16;
    return v.f;
}
static __device__ __forceinline__ unsigned int cvtpk(float lo, float hi) {
    unsigned int r;
    asm volatile("v_cvt_pk_bf16_f32 %0, %1, %2" : "=v"(r) : "v"(lo), "v"(hi));
    return r;
}
static __device__ __forceinline__ float exp2f_fast(float x) {
    float r; asm volatile("v_exp_f32 %0, %1" : "=v"(r) : "v"(x)); return r;
}
static __device__ __forceinline__ void gload_lds16(const void* g, void* l) {
    __builtin_amdgcn_global_load_lds(
        (const __attribute__((address_space(1))) unsigned int*)g,
        (__attribute__((address_space(3))) unsigned int*)l, 16, 0, 0);
}

// ---------------- fused prep: LN1 (wave/row) + mask scan + rope tables + weight converts ----------------
__global__ void prep_kernel(const float* __restrict__ x, u16* __restrict__ h1,
                            const float* __restrict__ gammas, const float* __restrict__ betas,
                            const float* __restrict__ wq, const float* __restrict__ wk,
                            const float* __restrict__ wv, const float* __restrict__ wo,
                            const float* __restrict__ w1, const float* __restrict__ w2,
                            u16* __restrict__ wqkvT, u16* __restrict__ woT,
                            u16* __restrict__ w1T, u16* __restrict__ w2T,
                            const int* __restrict__ mask, float* __restrict__ maskc,
                            int* __restrict__ invidx, int* __restrict__ nkp,
                            float* __restrict__ ct, float* __restrict__ st) {
    __shared__ float smem[1056];
    int b = blockIdx.x;
    int t = threadIdx.x;
    if (b < SEQ / 4) {                          // LN1: 4 rows/block, one wave each, no LDS
        int wv_ = t >> 6, lane = t & 63;
        int row = b * 4 + wv_;
        const float* xr = x + (size_t)row * DIM + lane * 8;
        float4 a0 = *(const float4*)xr;
        float4 a1 = *(const float4*)(xr + 4);
        float f[8] = {a0.x, a0.y, a0.z, a0.w, a1.x, a1.y, a1.z, a1.w};
        float s = 0.f, qs = 0.f;
#pragma unroll
        for (int i = 0; i < 8; i++) { s += f[i]; qs += f[i] * f[i]; }
#pragma unroll
        for (int o = 1; o < 64; o <<= 1) {
            s  += __shfl_xor(s, o, 64);
            qs += __shfl_xor(qs, o, 64);
        }
        float mean = s / DIM;
        float var  = qs / DIM - mean * mean;
        float rstd = rsqrtf(var + 1e-5f);
        float g = gammas[0], be = betas[0];
        u16x8 res;
#pragma unroll
        for (int i = 0; i < 8; i += 2) {
            unsigned int pk = cvtpk(g * ((f[i] - mean) * rstd) + be,
                                    g * ((f[i + 1] - mean) * rstd) + be);
            res[i]     = (u16)(pk & 0xffff);
            res[i + 1] = (u16)(pk >> 16);
        }
        *(u16x8*)(h1 + (size_t)row * DIM + lane * 8) = res;
        return;
    }
    b -= SEQ / 4;
    if (b < 1) {                                // mask-compaction scan (1 block, 256 thr x 16)
        __shared__ int cnt[256];
        int base = t * 16;
        int loc[16]; int c = 0;
#pragma unroll
        for (int i = 0; i < 16; i++) { loc[i] = mask[base + i]; c += (loc[i] != 0); }
        cnt[t] = c;
        __syncthreads();
        for (int o = 1; o < 256; o <<= 1) {
            int v = (t >= o) ? cnt[t - o] : 0;
            __syncthreads();
            cnt[t] += v;
            __syncthreads();
        }
        int pos = cnt[t] - c;                   // exclusive prefix
        int total = cnt[255];
#pragma unroll
        for (int i = 0; i < 16; i++)
            invidx[base + i] = loc[i] ? pos++ : -1;
#pragma unroll
        for (int i = 0; i < 16; i++)
            maskc[base + i] = (base + i < total) ? 0.0f : MASK_OFF;
        if (t == 0) *nkp = total;
        return;
    }
    b -= 1;
    if (b < 256) {                              // rope cos/sin tables: [s][i], i<16
        int idx = b * 256 + t;                  // 65536 = 4096*16
        int s = idx >> 4, i = idx & 15;
        float invf = expf(-(float)i * (9.2103403719761836f / 16.0f));  // 10000^(-i/16)
        float freq = (float)s * invf;
        ct[idx] = cosf(freq);
        st[idx] = sinf(freq);
        return;
    }
    b -= 256;
    const float* src; u16* dst; int K, N; float scale = 1.f;
    if (b < 256)       { src = wq; dst = wqkvT;            K = 512;  N = 512; scale = QSCALE; }
    else if (b < 512)  { src = wk; dst = wqkvT + 512*512;  K = 512;  N = 512; b -= 256; }
    else if (b < 768)  { src = wv; dst = wqkvT + 1024*512; K = 512;  N = 512; b -= 512; }
    else if (b < 1024) { src = wo; dst = woT;              K = 512;  N = 512; b -= 768; }
    else if (b < 2048) { src = w1; dst = w1T;              K = 512;  N = 2048; b -= 1024; }
    else               { src = w2; dst = w2T;              K = 2048; N = 512;  b -= 2048; }
    float (*tile)[33] = (float(*)[33])smem;
    int tiles_x = N / 32;
    int n0 = (b % tiles_x) * 32, k0 = (b / tiles_x) * 32;
    int tx = t & 31, ty = t >> 5;               // 32 x 8
#pragma unroll
    for (int i = 0; i < 4; i++) {
        int kk = ty + i * 8;
        tile[kk][tx] = src[(size_t)(k0 + kk) * N + n0 + tx];
    }
    __syncthreads();
#pragma unroll
    for (int i = 0; i < 4; i++) {
        int nn = ty + i * 8;
        dst[(size_t)(n0 + nn) * K + k0 + tx] = f2bf(scale * tile[tx][nn]);
    }
}

// ---------------- bf16 MFMA GEMM, 64x128 tile (qkv): 3 blocks/CU exact, balanced ----------------
__global__ __launch_bounds__(256, 3) void gemm_qkv(
    const u16* __restrict__ A, const u16* __restrict__ WT,
    void* __restrict__ Cq, void* __restrict__ Ck, void* __restrict__ Cv,
    const float* __restrict__ ct, const float* __restrict__ st,
    const int* __restrict__ invidx,
    int M, int N, int K)
{
    __shared__ __align__(16) u16 At[2][64 * 64];    //  8 KB per buf
    __shared__ __align__(16) u16 Bt[2][128 * 64];   // 16 KB per buf
    const int t = threadIdx.x, lane = t & 63, w = t >> 6;
    const int wm = w >> 1, wn = w & 1;
    const int n0 = blockIdx.x * 128, m0 = blockIdx.y * 64;
    const int l15 = lane & 15, l4 = lane >> 4;

    f32x4 acc[2][4];
#pragma unroll
    for (int m = 0; m < 2; m++)
#pragma unroll
        for (int n = 0; n < 4; n++) acc[m][n] = (f32x4){0.f, 0.f, 0.f, 0.f};

    auto stage = [&](int buf, int k0) {
#pragma unroll
        for (int i = 0; i < 2; i++) {            // A: 64 rows x 8 chunks = 512
            int c = (w * 2 + i) * 64 + lane;
            int r = c >> 3, j = (c & 7) ^ (r & 7);
            gload_lds16(A + (size_t)(m0 + r) * K + k0 + j * 8,
                        (char*)At[buf] + (w * 2 + i) * 1024);
        }
#pragma unroll
        for (int i = 0; i < 4; i++) {            // B: 128 rows x 8 chunks = 1024
            int c = (w * 4 + i) * 64 + lane;
            int r = c >> 3, j = (c & 7) ^ (r & 7);
            gload_lds16(WT + (size_t)(n0 + r) * K + k0 + j * 8,
                        (char*)Bt[buf] + (w * 4 + i) * 1024);
        }
    };

    const int NT = K / 64;
    stage(0, 0);
    for (int ti = 0; ti < NT; ti++) {
        const int cur = ti & 1;
        asm volatile("s_waitcnt vmcnt(0)" ::: "memory");
        __syncthreads();
        if (ti + 1 < NT) stage(cur ^ 1, (ti + 1) * 64);
        __builtin_amdgcn_s_setprio(1);
#pragma unroll
        for (int kk = 0; kk < 2; kk++) {
            bf16x8 af[2], bfr[4];
#pragma unroll
            for (int m = 0; m < 2; m++) {
                int row = wm * 32 + m * 16 + l15;
                af[m] = *(bf16x8*)((char*)At[cur] + row * 128 +
                                   ((kk * 64 + l4 * 16) ^ ((row & 7) << 4)));
            }
#pragma unroll
            for (int n = 0; n < 4; n++) {
                int row = wn * 64 + n * 16 + l15;
                bfr[n] = *(bf16x8*)((char*)Bt[cur] + row * 128 +
                                    ((kk * 64 + l4 * 16) ^ ((row & 7) << 4)));
            }
#pragma unroll
            for (int m = 0; m < 2; m++)
#pragma unroll
                for (int n = 0; n < 4; n++)
                    acc[m][n] = __builtin_amdgcn_mfma_f32_16x16x32_bf16(
                        af[m], bfr[n], acc[m][n], 0, 0, 0);
        }
        __builtin_amdgcn_s_setprio(0);
    }

    // epilogue: rope on q/k head-cols < 32, split-scatter K/V to compacted slots
    const int which = (n0 + wn * 64) >> 9;      // constant per wave (128 | 512)
#pragma unroll
    for (int m = 0; m < 2; m++)
#pragma unroll
        for (int rr = 0; rr < 4; rr++) {
            int row = m0 + wm * 32 + m * 16 + l4 * 4 + rr;
            int orow = (which > 0) ? invidx[row] : row;
#pragma unroll
            for (int n = 0; n < 4; n++) {
                int colg = n0 + wn * 64 + n * 16 + l15;
                float cv = acc[m][n][rr];
                if (which < 2 && n < 2) {        // RoPE (head-col = n*16+l15 < 32)
                    float partner = __shfl_xor(cv, 1, 64);
                    int i = (n * 16 + l15) >> 1;
                    float cc = ct[row * 16 + i], ss = st[row * 16 + i];
                    cv = (l15 & 1) ? (cv * cc + partner * ss) : (cv * cc - partner * ss);
                }
                if (orow >= 0) {
                    u16* dst = which == 0 ? (u16*)Cq : which == 1 ? (u16*)Ck : (u16*)Cv;
                    dst[(size_t)orow * 512 + (colg & 511)] = f2bf(cv);
                }
            }
        }
}

// ---------------- bf16 MFMA GEMM, 128x128 tile (ffn1) ----------------
constexpr int FLAG_GELU = 2;
__global__ __launch_bounds__(256) void gemm128(
    const u16* __restrict__ A, const u16* __restrict__ WT,
    const float* __restrict__ bias,
    void* __restrict__ Cq,
    int M, int N, int K, int flags)
{
    __shared__ __align__(16) u16 At[2][128 * 64];   // 16 KB per buf, swizzled image
    __shared__ __align__(16) u16 Bt[2][128 * 64];
    const int t = threadIdx.x, lane = t & 63, w = t >> 6;
    const int wm = w >> 1, wn = w & 1;
    const int n0 = blockIdx.x * 128, m0 = blockIdx.y * 128;
    const int l15 = lane & 15, l4 = lane >> 4;

    f32x4 acc[4][4];
#pragma unroll
    for (int m = 0; m < 4; m++)
#pragma unroll
        for (int n = 0; n < 4; n++) acc[m][n] = (f32x4){0.f, 0.f, 0.f, 0.f};

    auto stage = [&](int buf, int k0) {
#pragma unroll
        for (int i = 0; i < 4; i++) {
            int c = (w * 4 + i) * 64 + lane;
            int r = c >> 3, j = (c & 7) ^ (r & 7);
            gload_lds16(A + (size_t)(m0 + r) * K + k0 + j * 8,
                        (char*)At[buf] + (w * 4 + i) * 1024);
            gload_lds16(WT + (size_t)(n0 + r) * K + k0 + j * 8,
                        (char*)Bt[buf] + (w * 4 + i) * 1024);
        }
    };

    const int NT = K / 64;
    stage(0, 0);
    for (int ti = 0; ti < NT; ti++) {
        const int cur = ti & 1;
        asm volatile("s_waitcnt vmcnt(0)" ::: "memory");
        __syncthreads();
        if (ti + 1 < NT) stage(cur ^ 1, (ti + 1) * 64);
        __builtin_amdgcn_s_setprio(1);
#pragma unroll
        for (int kk = 0; kk < 2; kk++) {
            bf16x8 af[4], bfr[4];
#pragma unroll
            for (int m = 0; m < 4; m++) {
                int row = wm * 64 + m * 16 + l15;
                af[m] = *(bf16x8*)((char*)At[cur] + row * 128 +
                                   ((kk * 64 + l4 * 16) ^ ((row & 7) << 4)));
            }
#pragma unroll
            for (int n = 0; n < 4; n++) {
                int row = wn * 64 + n * 16 + l15;
                bfr[n] = *(bf16x8*)((char*)Bt[cur] + row * 128 +
                                    ((kk * 64 + l4 * 16) ^ ((row & 7) << 4)));
            }
#pragma unroll
            for (int m = 0; m < 4; m++)
#pragma unroll
                for (int n = 0; n < 4; n++)
                    acc[m][n] = __builtin_amdgcn_mfma_f32_16x16x32_bf16(
                        af[m], bfr[n], acc[m][n], 0, 0, 0);
        }
        __builtin_amdgcn_s_setprio(0);
    }

    // epilogue (bias / gelu / bf16)
#pragma unroll
    for (int m = 0; m < 4; m++)
#pragma unroll
        for (int rr = 0; rr < 4; rr++) {
            int row = m0 + wm * 64 + m * 16 + l4 * 4 + rr;
#pragma unroll
            for (int n = 0; n < 4; n++) {
                int colg = n0 + wn * 64 + n * 16 + l15;
                float cv = acc[m][n][rr];
                if (bias) cv += bias[colg];
                if (flags & FLAG_GELU) cv = 0.5f * cv * (1.0f + erff(cv * 0.70710678118f));
                ((u16*)Cq)[(size_t)row * N + colg] = f2bf(cv);
            }
        }
}

// ---------------- split-K GEMM: 128x128 tile, 4 K-splits, bf16 partials (wo AND w2) ----------------
// Grid (N/128, M/128, 4) = 512 blocks @ 64 KB = 2/CU exact, balanced.
__global__ __launch_bounds__(256) void gemm_w2split(
    const u16* __restrict__ A, const u16* __restrict__ WT,
    u16* __restrict__ p0, u16* __restrict__ p1,
    u16* __restrict__ p2, u16* __restrict__ p3,
    int M, int N, int K)
{
    __shared__ __align__(16) u16 At[2][128 * 64];
    __shared__ __align__(16) u16 Bt[2][128 * 64];
    const int t = threadIdx.x, lane = t & 63, w = t >> 6;
    const int wm = w >> 1, wn = w & 1;
    const int n0 = blockIdx.x * 128, m0 = blockIdx.y * 128;
    const int z = blockIdx.z;
    const int kbase = z * (K / 4);
    const int l15 = lane & 15, l4 = lane >> 4;

    f32x4 acc[4][4];
#pragma unroll
    for (int m = 0; m < 4; m++)
#pragma unroll
        for (int n = 0; n < 4; n++) acc[m][n] = (f32x4){0.f, 0.f, 0.f, 0.f};

    auto stage = [&](int buf, int k0) {
#pragma unroll
        for (int i = 0; i < 4; i++) {
            int c = (w * 4 + i) * 64 + lane;
            int r = c >> 3, j = (c & 7) ^ (r & 7);
            gload_lds16(A + (size_t)(m0 + r) * K + k0 + j * 8,
                        (char*)At[buf] + (w * 4 + i) * 1024);
            gload_lds16(WT + (size_t)(n0 + r) * K + k0 + j * 8,
                        (char*)Bt[buf] + (w * 4 + i) * 1024);
        }
    };

    const int NT = (K / 4) / 64;
    stage(0, kbase);
    for (int ti = 0; ti < NT; ti++) {
        const int cur = ti & 1;
        asm volatile("s_waitcnt vmcnt(0)" ::: "memory");
        __syncthreads();
        if (ti + 1 < NT) stage(cur ^ 1, kbase + (ti + 1) * 64);
        __builtin_amdgcn_s_setprio(1);
#pragma unroll
        for (int kk = 0; kk < 2; kk++) {
            bf16x8 af[4], bfr[4];
#pragma unroll
            for (int m = 0; m < 4; m++) {
                int row = wm * 64 + m * 16 + l15;
                af[m] = *(bf16x8*)((char*)At[cur] + row * 128 +
                                   ((kk * 64 + l4 * 16) ^ ((row & 7) << 4)));
            }
#pragma unroll
            for (int n = 0; n < 4; n++) {
                int row = wn * 64 + n * 16 + l15;
                bfr[n] = *(bf16x8*)((char*)Bt[cur] + row * 128 +
                                    ((kk * 64 + l4 * 16) ^ ((row & 7) << 4)));
            }
#pragma unroll
            for (int m = 0; m < 4; m++)
#pragma unroll
                for (int n = 0; n < 4; n++)
                    acc[m][n] = __builtin_amdgcn_mfma_f32_16x16x32_bf16(
                        af[m], bfr[n], acc[m][n], 0, 0, 0);
        }
        __builtin_amdgcn_s_setprio(0);
    }

    u16* pz = (z == 0) ? p0 : (z == 1) ? p1 : (z == 2) ? p2 : p3;
#pragma unroll
    for (int m = 0; m < 4; m++)
#pragma unroll
        for (int rr = 0; rr < 4; rr++) {
            int row = m0 + wm * 64 + m * 16 + l4 * 4 + rr;
#pragma unroll
            for (int n = 0; n < 4; n++) {
                int colg = n0 + wn * 64 + n * 16 + l15;
                pz[(size_t)row * N + colg] = f2bf(acc[m][n][rr]);
            }
        }
}

// ---------------- wo combine + LN2 fused: wave-per-row ----------------
// v = x + (p0+p1+p2+p3) + bo; x2b = bf16(v); h2b = bf16(LN(v)*g + b).
__global__ void wo_combine_ln(const u16* __restrict__ p0, const u16* __restrict__ p1,
                              const u16* __restrict__ p2, const u16* __restrict__ p3,
                              const float* __restrict__ x, const float* __restrict__ bo,
                              const float* __restrict__ gammas, const float* __restrict__ betas,
                              u16* __restrict__ x2b, u16* __restrict__ h2b) {
    int t = threadIdx.x;
    int wv_ = t >> 6, lane = t & 63;
    int row = blockIdx.x * 4 + wv_;
    int col = lane * 8;
    size_t off = (size_t)row * DIM + col;
    u16x8 a = *(const u16x8*)(p0 + off);
    u16x8 b = *(const u16x8*)(p1 + off);
    u16x8 c = *(const u16x8*)(p2 + off);
    u16x8 d = *(const u16x8*)(p3 + off);
    float4 x0 = *(const float4*)(x + off);
    float4 x1 = *(const float4*)(x + off + 4);
    float4 b0 = *(const float4*)(bo + col);
    float4 b1 = *(const float4*)(bo + col + 4);
    float xv[8] = {x0.x, x0.y, x0.z, x0.w, x1.x, x1.y, x1.z, x1.w};
    float bv[8] = {b0.x, b0.y, b0.z, b0.w, b1.x, b1.y, b1.z, b1.w};
    float v[8];
    float s = 0.f, qs = 0.f;
#pragma unroll
    for (int j = 0; j < 8; j++) {
        v[j] = xv[j] + bv[j] + bf2f(a[j]) + bf2f(b[j]) + bf2f(c[j]) + bf2f(d[j]);
        s += v[j]; qs += v[j] * v[j];
    }
#pragma unroll
    for (int o = 1; o < 64; o <<= 1) {
        s  += __shfl_xor(s, o, 64);
        qs += __shfl_xor(qs, o, 64);
    }
    float mean = s / DIM;
    float var  = qs / DIM - mean * mean;
    float rstd = rsqrtf(var + 1e-5f);
    float g = gammas[1], be = betas[1];
    u16x8 rx, rh;
#pragma unroll
    for (int j = 0; j < 8; j += 2) {
        unsigned int px = cvtpk(v[j], v[j + 1]);
        unsigned int ph = cvtpk(g * ((v[j] - mean) * rstd) + be,
                                g * ((v[j + 1] - mean) * rstd) + be);
        rx[j] = (u16)(px & 0xffff); rx[j + 1] = (u16)(px >> 16);
        rh[j] = (u16)(ph & 0xffff); rh[j + 1] = (u16)(ph >> 16);
    }
    *(u16x8*)(x2b + off) = rx;
    *(u16x8*)(h2b + off) = rh;
}

// ---------------- w2 combine: out = x2b + p0+p1+p2+p3 + b2 (f32 out) ----------------
__global__ void w2_combine(const u16* __restrict__ p0, const u16* __restrict__ p1,
                           const u16* __restrict__ p2, const u16* __restrict__ p3,
                           const u16* __restrict__ x2b, const float* __restrict__ b2,
                           float* __restrict__ out) {
    int t = threadIdx.x;               // 256 threads = 4 rows x 64 col-groups of 8
    int row = blockIdx.x * 4 + (t >> 6);
    int col = (t & 63) * 8;
    size_t off = (size_t)row * DIM + col;
    u16x8 a = *(const u16x8*)(p0 + off);
    u16x8 b = *(const u16x8*)(p1 + off);
    u16x8 c = *(const u16x8*)(p2 + off);
    u16x8 d = *(const u16x8*)(p3 + off);
    u16x8 xr = *(const u16x8*)(x2b + off);
    float4 bb0 = *(const float4*)(b2 + col);
    float4 bb1 = *(const float4*)(b2 + col + 4);
    float bias[8] = {bb0.x, bb0.y, bb0.z, bb0.w, bb1.x, bb1.y, bb1.z, bb1.w};
    float res[8];
#pragma unroll
    for (int j = 0; j < 8; j++)
        res[j] = bf2f(xr[j]) + bf2f(a[j]) + bf2f(b[j]) + bf2f(c[j]) + bf2f(d[j]) + bias[j];
    *(float4*)(out + off)     = (float4){res[0], res[1], res[2], res[3]};
    *(float4*)(out + off + 4) = (float4){res[4], res[5], res[6], res[7]};
}

// ---------------- per-head transpose of compacted V: vc (nk, NH*HD) -> vTc (NH, HD, SEQ) ----------------
__global__ void transpose_c(const u16* __restrict__ vc, const int* __restrict__ nkp,
                            u16* __restrict__ vTc) {
    int nk = *nkp;
    int s0 = blockIdx.x * 64;
    if (s0 >= ((nk + 63) & ~63)) return;        // past last compacted tile
    __shared__ __align__(16) u16 tile[64][80];
    int h = blockIdx.y;
    int t = threadIdx.x;               // 256
#pragma unroll
    for (int p = 0; p < 2; p++) {
        int c = p * 256 + t;
        int r = c >> 3, j = c & 7;
        u16x8 vv = {};
        if (s0 + r < nk)
            vv = *(const u16x8*)(vc + (size_t)(s0 + r) * DIM + h * HDIM + j * 8);
        *(u16x8*)&tile[r][j * 8] = vv;
    }
    __syncthreads();
#pragma unroll
    for (int p = 0; p < 2; p++) {
        int c = p * 256 + t;
        int d = c >> 3, j = c & 7;
        u16x8 vv;
#pragma unroll
        for (int i = 0; i < 8; i++) vv[i] = tile[j * 8 + i][d];
        *(u16x8*)(vTc + ((size_t)h * HDIM + d) * SEQ + s0 + j * 8) = vv;
    }
}

// ---------------- flash attention over COMPACTED keys: 32 q/wave, KV-split x3, LDS-P ----------------
__global__ __launch_bounds__(256, 3) void fattn_kernel(
    const u16* __restrict__ q, const u16* __restrict__ k,
    const u16* __restrict__ vT, const float* __restrict__ maskc,
    const int* __restrict__ nkp,
    u16* __restrict__ Opart, float* __restrict__ lpart)
{
    __shared__ __align__(16) u16 k_s[2][64 * 64];     // 16 KB [buf][key][d] swizzled image
    __shared__ __align__(16) u16 vt_s[2][64 * 64];    // 16 KB [buf][d][key] swizzled image
    __shared__ __align__(16) u16 p_s[4][32 * 64];     // 16 KB per-wave [q][key] swizzled

    const int t = threadIdx.x;
    const int lane = t & 63;
    const int w = t >> 6;
    const int h = blockIdx.x;
    const int q0 = blockIdx.y * 128;
    const int split = blockIdx.z;
    const int nk = *nkp;
    const int ntiles = (nk + 63) >> 6;
    const int tstart = (split * ntiles) / 3;
    const int tend   = ((split + 1) * ntiles) / 3;
    const int l15 = lane & 15, g = lane >> 4;

    // Q as B-frags, straight from global: q-row = q0+w*32+qh*16+l15, d = g*8+j (+32)
    bf16x8 qf[2][2];
#pragma unroll
    for (int qh = 0; qh < 2; qh++) {
        const u16* qrow = q + (size_t)(q0 + w * 32 + qh * 16 + l15) * DIM + h * HDIM;
        qf[qh][0] = *(const bf16x8*)(qrow + g * 8);
        qf[qh][1] = *(const bf16x8*)(qrow + g * 8 + 32);
    }

    // ones A-fragment (bf16 1.0 = 0x3F80) for the row-sum MFMA
    const bf16x8 ones = (bf16x8){16256, 16256, 16256, 16256, 16256, 16256, 16256, 16256};

    f32x4 O[2][4];                    // O^T: [qh][dt], reg r -> d = dt*16+4g+r, col q
    f32x4 lacc[2];                    // row-sum accumulator (all regs equal)
#pragma unroll
    for (int qh = 0; qh < 2; qh++) {
#pragma unroll
        for (int dt = 0; dt < 4; dt++) O[qh][dt] = (f32x4){0.f, 0.f, 0.f, 0.f};
        lacc[qh] = (f32x4){0.f, 0.f, 0.f, 0.f};
    }

    char* pbase = (char*)p_s[w];
    const int psw = (l15 & 7) << 4;

    auto stage = [&](int buf, int kb2) {
#pragma unroll
        for (int i = 0; i < 2; i++) {
            int c = (w * 2 + i) * 64 + lane;
            int r = c >> 3, j = (c & 7) ^ (r & 7);
            gload_lds16(k + (size_t)(kb2 + r) * DIM + h * HDIM + j * 8,
                        (char*)k_s + buf * 8192 + (w * 2 + i) * 1024);
            gload_lds16(vT + ((size_t)h * HDIM + r) * SEQ + kb2 + j * 8,
                        (char*)vt_s + buf * 8192 + (w * 2 + i) * 1024);
        }
    };

    if (tstart < tend) stage(0, tstart * 64);
    for (int ti = tstart; ti < tend; ti++) {
        const int cur = (ti - tstart) & 1;
        const int kb = ti * 64;
        asm volatile("s_waitcnt vmcnt(0)" ::: "memory");
        __syncthreads();
        if (ti + 1 < tend) stage(cur ^ 1, kb + 64);

        char* kcur = (char*)k_s + cur * 8192;
        char* vcur = (char*)vt_s + cur * 8192;

        // ---- QK^T (swapped): 2 independent chains (qh) off shared K A-frags ----
        f32x4 sacc[2][4];
        __builtin_amdgcn_s_setprio(1);
#pragma unroll
        for (int kt = 0; kt < 4; kt++) {
            int key = kt * 16 + l15;
            int ksw = (key & 7) << 4;
            char* kbase = kcur + key * 128;
            bf16x8 a0 = *(bf16x8*)(kbase + ((g * 16)      ^ ksw));
            bf16x8 a1 = *(bf16x8*)(kbase + ((g * 16 + 64) ^ ksw));
#pragma unroll
            for (int qh = 0; qh < 2; qh++) {
                f32x4 z = (f32x4){0.f, 0.f, 0.f, 0.f};
                z = __builtin_amdgcn_mfma_f32_16x16x32_bf16(a0, qf[qh][0], z, 0, 0, 0);
                z = __builtin_amdgcn_mfma_f32_16x16x32_bf16(a1, qf[qh][1], z, 0, 0, 0);
                sacc[qh][kt] = z;
            }
        }
        __builtin_amdgcn_s_setprio(0);

        // ---- P = exp2(sacc) [+pad mask only on the LAST tile] + b64 pack ----
        const bool haspad = (ti == ntiles - 1);
        if (!haspad) {
#pragma unroll
            for (int qh = 0; qh < 2; qh++)
#pragma unroll
                for (int kt = 0; kt < 4; kt++) {
                    float p0 = exp2f_fast(sacc[qh][kt][0]);
                    float p1 = exp2f_fast(sacc[qh][kt][1]);
                    float p2 = exp2f_fast(sacc[qh][kt][2]);
                    float p3 = exp2f_fast(sacc[qh][kt][3]);
                    uint2 pk;
                    pk.x = cvtpk(p0, p1);
                    pk.y = cvtpk(p2, p3);
                    int colb = (kt * 16 + g * 4) * 2;      // byte col, 8B aligned
                    *(uint2*)(pbase + (qh * 16 + l15) * 128 + (colb ^ psw)) = pk;
                }
        } else {
            float4 mf4[4];
#pragma unroll
            for (int kt = 0; kt < 4; kt++)
                mf4[kt] = *(const float4*)(maskc + kb + kt * 16 + g * 4);
#pragma unroll
            for (int qh = 0; qh < 2; qh++)
#pragma unroll
                for (int kt = 0; kt < 4; kt++) {
                    float p0 = exp2f_fast(sacc[qh][kt][0] + mf4[kt].x);
                    float p1 = exp2f_fast(sacc[qh][kt][1] + mf4[kt].y);
                    float p2 = exp2f_fast(sacc[qh][kt][2] + mf4[kt].z);
                    float p3 = exp2f_fast(sacc[qh][kt][3] + mf4[kt].w);
                    uint2 pk;
                    pk.x = cvtpk(p0, p1);
                    pk.y = cvtpk(p2, p3);
                    int colb = (kt * 16 + g * 4) * 2;
                    *(uint2*)(pbase + (qh * 16 + l15) * 128 + (colb ^ psw)) = pk;
                }
        }

        // ---- PV: O^T += V^T(A) @ P(B); lacc += ones @ P (row sums) ----
        __builtin_amdgcn_s_setprio(1);
#pragma unroll
        for (int h2 = 0; h2 < 2; h2++) {
            bf16x8 pb[2];
#pragma unroll
            for (int qh = 0; qh < 2; qh++)
                pb[qh] = *(bf16x8*)(pbase + (qh * 16 + l15) * 128 +
                                    (((h2 * 4 + g) * 16) ^ psw));
#pragma unroll
            for (int dt = 0; dt < 4; dt++) {
                int d = dt * 16 + l15;
                bf16x8 va = *(bf16x8*)(vcur + d * 128 +
                                       (((h2 * 4 + g) * 16) ^ ((d & 7) << 4)));
#pragma unroll
                for (int qh = 0; qh < 2; qh++)
                    O[qh][dt] = __builtin_amdgcn_mfma_f32_16x16x32_bf16(
                        va, pb[qh], O[qh][dt], 0, 0, 0);
            }
#pragma unroll
            for (int qh = 0; qh < 2; qh++)
                lacc[qh] = __builtin_amdgcn_mfma_f32_16x16x32_bf16(
                    ones, pb[qh], lacc[qh], 0, 0, 0);
        }
        __builtin_amdgcn_s_setprio(0);
    }

    // ---- epilogue: unnormalized partial O (bf16) + partial row sums ----
#pragma unroll
    for (int qh = 0; qh < 2; qh++) {
        float lrun = lacc[qh][0];     // every lane holds the full sum for its q-col
        int row = q0 + w * 32 + qh * 16 + l15;
        u16* orow = Opart + (size_t)split * SEQ * DIM + (size_t)row * DIM + h * HDIM;
#pragma unroll
        for (int dt = 0; dt < 4; dt++)
#pragma unroll
            for (int r = 0; r < 4; r += 2) {
                unsigned int pk = cvtpk(O[qh][dt][r], O[qh][dt][r + 1]);
                *(unsigned int*)(orow + dt * 16 + 4 * g + r) = pk;
            }
        if (g == 0)
            lpart[((size_t)split * NH + h) * SEQ + row] = lrun;
    }
}

// ---------------- combine: out = (O0+O1+O2) / (l0+l1+l2), bf16, u16x8 vectorized ----------------
__global__ void attn_combine(const u16* __restrict__ Opart, const float* __restrict__ lpart,
                             u16* __restrict__ out) {
    int t = threadIdx.x;               // 256 threads = 4 rows x 64 col-groups
    int row = blockIdx.x * 4 + (t >> 6);
    int col = (t & 63) * 8;
    int h = col >> 6;
    float l = lpart[(size_t)h * SEQ + row]
            + lpart[((size_t)NH + h) * SEQ + row]
            + lpart[((size_t)2 * NH + h) * SEQ + row];
    float inv = 1.0f / l;
    const size_t SD = (size_t)SEQ * DIM;
    const u16* base = Opart + (size_t)row * DIM + col;
    u16x8 ua = *(const u16x8*)(base);
    u16x8 ub = *(const u16x8*)(base + SD);
    u16x8 uc = *(const u16x8*)(base + 2 * SD);
    u16x8 res;
#pragma unroll
    for (int j = 0; j < 8; j += 2) {
        float o0 = bf2f(ua[j])     + bf2f(ub[j])     + bf2f(uc[j]);
        float o1 = bf2f(ua[j + 1]) + bf2f(ub[j + 1]) + bf2f(uc[j + 1]);
        unsigned int pk = cvtpk(o0 * inv, o1 * inv);
        res[j]     = (u16)(pk & 0xffff);
        res[j + 1] = (u16)(pk >> 16);
    }
    *(u16x8*)(out + (size_t)row * DIM + col) = res;
}

extern "C" void kernel_launch(void* const* d_in, const int* in_sizes, int n_in,
                              void* d_out, int out_size, void* d_ws, size_t ws_size,
                              hipStream_t stream) {
    const float* x      = (const float*)d_in[0];
    const float* gammas = (const float*)d_in[1];
    const float* betas  = (const float*)d_in[2];
    const float* wq     = (const float*)d_in[3];
    const float* wk     = (const float*)d_in[4];
    const float* wv     = (const float*)d_in[5];
    const float* wo     = (const float*)d_in[6];
    const float* bo     = (const float*)d_in[7];
    const float* w1     = (const float*)d_in[8];
    const float* b1     = (const float*)d_in[9];
    const float* w2     = (const float*)d_in[10];
    const float* b2     = (const float*)d_in[11];
    const int*   mask   = (const int*)d_in[12];
    float* out = (float*)d_out;

    // ---- workspace layout (bytes); peak <= 45 MB (proven R21) ----
    char* wsb = (char*)d_ws;
    u16*   h1b   = (u16*)(wsb + 0);                 // 4 MB; LN1 out; then attnb; f1b spans 0-16
    u16*   kc    = (u16*)(wsb + (4ull  << 20));     // 4 MB compacted K
    u16*   vc    = (u16*)(wsb + (8ull  << 20));     // 4 MB compacted V (dead after transpose)
    u16*   vTc   = (u16*)(wsb + (12ull << 20));     // 4 MB compacted V^T (dead after fattn)
    u16*   qb    = (u16*)(wsb + (16ull << 20));     // 4 MB; dead after fattn -> h2b
    u16*   Opart = (u16*)(wsb + (20ull << 20));     // 12 MB: 3 splits x 4 MB (20-32)
    u16*   x2b   = (u16*)(wsb + (20ull << 20));     // 4 MB bf16 x2 (over dead Opart0; LIVE at end)
    u16*   wqkvT = (u16*)(wsb + (32ull << 20));     // 1.5 MB
    u16*   woT   = wqkvT + 1536 * 512;              // 0.5 MB
    u16*   w1T   = woT   + 512 * 512;               // 2 MB
    u16*   w2T   = w1T   + 2048 * 512;              // 2 MB (ends 38 MB)
    float* maskc = (float*)(wsb + (38ull << 20));   // 16 KB
    int*   invidx= (int*)(wsb + (38ull << 20) + (64 << 10));   // 16 KB
    int*   nkp   = (int*)(wsb + (38ull << 20) + (128 << 10));  // 4 B
    float* ct    = (float*)(wsb + (39ull << 20));   // 256 KB
    float* st    = ct + 65536;                      // 256 KB
    float* lpart = (float*)(wsb + (40ull << 20));   // 384 KB
    // wo split-K partials (phase: after attn_combine, before wo_combine_ln):
    //   dead regions: Opart splits 1,2 (24,28), vTc (12), vc (8)
    u16*   op0   = (u16*)(wsb + (24ull << 20));
    u16*   op1   = (u16*)(wsb + (28ull << 20));
    u16*   op2   = (u16*)(wsb + (12ull << 20));
    u16*   op3   = (u16*)(wsb + (8ull  << 20));
    // w2 split-K partials (phase: after ffn1): dead: Opart tail (24,28), h2b (16), free tail (41)
    u16*   wp0   = (u16*)(wsb + (24ull << 20));
    u16*   wp1   = (u16*)(wsb + (28ull << 20));
    u16*   wp2   = (u16*)(wsb + (16ull << 20));
    u16*   wp3   = (u16*)(wsb + (41ull << 20));
    u16*   f1b   = h1b;                             // 16 MB spanning 0-16 (FFN phase)
    u16*   h2b   = qb;
    u16*   attnb = h1b;

    // 0. fused prep: LN1 + mask scan (invidx) + rope tables + weight converts
    prep_kernel<<<SEQ / 4 + 1 + 256 + 3072, 256, 0, stream>>>(
        x, h1b, gammas, betas, wq, wk, wv, wo, w1, w2,
        wqkvT, woT, w1T, w2T, mask, maskc, invidx, nkp, ct, st);
    // 1. fused QKV projection + RoPE; 64x128 tiles (768 blocks = 3/CU exact)
    gemm_qkv<<<dim3(1536 / 128, SEQ / 64), 256, 0, stream>>>(
        h1b, wqkvT, qb, kc, vc, ct, st, invidx, SEQ, 1536, DIM);
    // 2. per-head transpose of compacted V
    transpose_c<<<dim3(SEQ / 64, NH), 256, 0, stream>>>(vc, nkp, vTc);
    // 3. attention over compacted keys, KV-split x3 (partials), then combine
    fattn_kernel<<<dim3(NH, SEQ / 128, KSPLIT), 256, 0, stream>>>(
        qb, kc, vTc, maskc, nkp, Opart, lpart);
    attn_combine<<<SEQ / 4, 256, 0, stream>>>(Opart, lpart, attnb);
    // 4. wo split-K x4 (128x128 tiles, 512 blocks = 2/CU exact), bf16 partials
    gemm_w2split<<<dim3(DIM / 128, SEQ / 128, 4), 256, 0, stream>>>(
        attnb, woT, op0, op1, op2, op3, SEQ, DIM, DIM);
    // 5. wo combine + LN2 fused (wave-per-row): x2b = bf16(x+attn@wo+bo); h2b = LN
    wo_combine_ln<<<SEQ / 4, 256, 0, stream>>>(
        op0, op1, op2, op3, x, bo, gammas, betas, x2b, h2b);
    // 6. f1 = gelu(h2@w1 + b1) (bf16), 128x128 tiles (512 blocks = 2/CU exact)
    gemm128<<<dim3(FFD / 128, SEQ / 128), 256, 0, stream>>>(
        h2b, w1T, b1, f1b, SEQ, FFD, DIM, FLAG_GELU);
    // 7. w2 split-K x4 (128x128 tiles, 512 blocks = 2/CU exact), bf16 partials
    gemm_w2split<<<dim3(DIM / 128, SEQ / 128, 4), 256, 0, stream>>>(
        f1b, w2T, wp0, wp1, wp2, wp3, SEQ, DIM, FFD);
    // 8. out = x2b + sum(partials) + b2 (f32)
    w2_combine<<<SEQ / 4, 256, 0, stream>>>(wp0, wp1, wp2, wp3, x2b, b2, out);
}